// Round 7
// baseline (164.708 us; speedup 1.0000x reference)
//
#include <hip/hip_runtime.h>
#include <hip/hip_cooperative_groups.h>
#include <math.h>

namespace cg = cooperative_groups;

// Problem constants
#define BB_ 2      // batch
#define CC_ 6      // channels
#define NN_ 2048   // points
#define KK_ 64     // keypoints
#define NS_ 32     // neighbors
#define DD_ 32     // feat dim
#define NC_ 216    // candidate grid (6^3)
#define HH_ 64     // hidden dim

// Workspace layout (in floats)
#define OFF_SRC_PACK 0                    // B*N float4 = 16384 floats
#define OFF_TGT_PACK 16384                // 16384
#define OFF_SRC_FEAT 32768                // B*N*D = 131072
#define OFF_TGT_FEAT 163840               // 131072
#define OFF_W        294912               // B*N = 4096
#define OFF_CENTERS  299008               // B*K*3 = 384
#define OFF_XFORM    299392               // 384
#define OFF_SRCDFE   299776               // B*K*D = 4096
#define OFF_NNT      303872               // B*K*NC ints = 27648

// Order-preserving bijection float -> uint32 (ascending)
__device__ __forceinline__ unsigned sortable_f32(float f) {
    unsigned u = __float_as_uint(f);
    return (u & 0x80000000u) ? ~u : (u | 0x80000000u);
}
__device__ __forceinline__ float unsortable_f32(unsigned s) {
    unsigned u = (s & 0x80000000u) ? (s ^ 0x80000000u) : ~s;
    return __uint_as_float(u);
}

// Full ascending bitonic sort of 64 u64 keys across the 64 lanes of a wave.
__device__ __forceinline__ unsigned long long wave_sort64_asc(unsigned long long key, int lane) {
#pragma unroll
    for (int k = 2; k <= 64; k <<= 1) {
#pragma unroll
        for (int j = k >> 1; j > 0; j >>= 1) {
            unsigned long long other = __shfl_xor(key, j);
            bool lower = (lane & j) == 0;
            bool asc = (lane & k) == 0;
            bool takemin = (lower == asc);
            unsigned long long mn = key < other ? key : other;
            unsigned long long mx = key < other ? other : key;
            key = takemin ? mn : mx;
        }
    }
    return key;
}

// Two ascending sorted 64-runs -> smallest 64 of the union, ascending.
__device__ __forceinline__ unsigned long long merge_keep_min64(unsigned long long a, unsigned long long b, int lane) {
    unsigned long long br = __shfl(b, 63 - lane);
    unsigned long long m = a < br ? a : br;
#pragma unroll
    for (int j = 32; j > 0; j >>= 1) {
        unsigned long long other = __shfl_xor(m, j);
        bool lower = (lane & j) == 0;
        unsigned long long mn = m < other ? m : other;
        unsigned long long mx = m < other ? other : m;
        m = lower ? mn : mx;
    }
    return m;
}

// 9-wave (576 thread) select-64-smallest-of-2048: waves 0..7 take 4 keys/lane
// (contiguous 256-point slabs), produce per-wave sorted runs, LDS merge tree.
// keys must be provided by a functor-free caller: we inline it per call site.

struct MegaLds {
    union {
        float4 pk[NN_];                                      // cand role: 32 KB
        struct {
            unsigned long long runs[8 * 64];                 // 4 KB
            float hs[NS_][HH_];                              // 8 KB
            float outs[NS_][DD_];                            // 4 KB
        } s;
        float sims[NC_];
    };
};

// ==================== fused single-launch kernel ====================
__global__ __launch_bounds__(576) void mega_kernel(
        const float* __restrict__ src, const float* __restrict__ tgt,
        const float* __restrict__ R, const float* __restrict__ t,
        const float* __restrict__ W1, const float* __restrict__ b1,
        const float* __restrict__ W2, const float* __restrict__ b2,
        const float* __restrict__ Wwl, const float* __restrict__ bwl,
        const float* __restrict__ W3, const float* __restrict__ b3,
        const float* __restrict__ W4, const float* __restrict__ b4,
        float* __restrict__ ws, float* __restrict__ out) {
    cg::grid_group grid = cg::this_grid();
    __shared__ MegaLds u;
    int blk = blockIdx.x;
    int tid = threadIdx.x;                                   // 0..575

    // ---------------- Phase 0: feature extraction ----------------
    {
        int g = blk * 576 + tid;
        if (g < 2 * BB_ * NN_) {
            int cloud = g / (BB_ * NN_);
            int r = g - cloud * BB_ * NN_;
            int b = r / NN_, n = r % NN_;
            const float* pts = cloud ? tgt : src;
            float x[CC_];
#pragma unroll
            for (int c = 0; c < CC_; ++c) x[c] = pts[(b * CC_ + c) * NN_ + n];
            float bb;
            {
#pragma clang fp contract(off)
                bb = (x[0] * x[0] + x[1] * x[1]) + x[2] * x[2];
            }
            float4* pack = (float4*)(ws + (cloud ? OFF_TGT_PACK : OFF_SRC_PACK));
            pack[b * NN_ + n] = make_float4(x[0], x[1], x[2], bb);
            float h[HH_];
#pragma unroll
            for (int tt = 0; tt < HH_; ++tt) {
                float s = b1[tt];
#pragma unroll
                for (int c = 0; c < CC_; ++c) s += x[c] * W1[c * HH_ + tt];
                h[tt] = fmaxf(s, 0.f);
            }
            float* feat = ws + (cloud ? OFF_TGT_FEAT : OFF_SRC_FEAT) + (size_t)(b * NN_ + n) * DD_;
            float wsum = 0.f;
#pragma unroll 4
            for (int d = 0; d < DD_; ++d) {
                float s = b2[d];
#pragma unroll
                for (int tt = 0; tt < HH_; ++tt) s += h[tt] * W2[tt * DD_ + d];
                s = fmaxf(s, 0.f);
                feat[d] = s;
                wsum += s * Wwl[d];
            }
            if (cloud == 0) (ws + OFF_W)[b * NN_ + n] = wsum + bwl[0];
        }
    }
    grid.sync();

    // ---------------- Phase 1: top-K keypoints (blocks 0..1) ----------------
    if (blk < BB_) {
        int b = blk;
        int w = tid >> 6, lane = tid & 63;
        const float* wv = ws + OFF_W + b * NN_;
        if (w < 8) {
            unsigned long long k4[4];
#pragma unroll
            for (int q = 0; q < 4; ++q) {
                int j = w * 256 + q * 64 + lane;
                k4[q] = ((unsigned long long)(~sortable_f32(wv[j])) << 32) | (unsigned)j;
            }
            unsigned long long m1 = merge_keep_min64(wave_sort64_asc(k4[0], lane),
                                                     wave_sort64_asc(k4[1], lane), lane);
            unsigned long long m2 = merge_keep_min64(wave_sort64_asc(k4[2], lane),
                                                     wave_sort64_asc(k4[3], lane), lane);
            u.s.runs[w * 64 + lane] = merge_keep_min64(m1, m2, lane);
        }
        __syncthreads();
#pragma unroll
        for (int lvl = 4; lvl >= 1; lvl >>= 1) {
            unsigned long long r = 0;
            if (w < lvl) r = merge_keep_min64(u.s.runs[w * 64 + lane], u.s.runs[(w + lvl) * 64 + lane], lane);
            __syncthreads();
            if (w < lvl) u.s.runs[w * 64 + lane] = r;
            __syncthreads();
        }
        if (tid < KK_) {
            int bi = (int)(u.s.runs[tid] & 0xFFFFFFFFu);
            float c3[3];
#pragma unroll
            for (int c = 0; c < CC_; ++c) {
                float v = src[(b * CC_ + c) * NN_ + bi];
                out[(b * KK_ + tid) * CC_ + c] = v;
                if (c < 3) c3[c] = v;
            }
            float* cen = ws + OFF_CENTERS + (b * KK_ + tid) * 3;
            cen[0] = c3[0]; cen[1] = c3[1]; cen[2] = c3[2];
            float* xf = ws + OFF_XFORM + (b * KK_ + tid) * 3;
#pragma unroll
            for (int i = 0; i < 3; ++i) {
#pragma clang fp contract(off)
                xf[i] = ((R[i * 3 + 0] * c3[0] + R[i * 3 + 1] * c3[1]) + R[i * 3 + 2] * c3[2]) + t[i];
            }
        }
    }
    grid.sync();

    // ---------------- Phase 2a: candidate NN (all 256 blocks) ----------------
    {
        int bk = blk >> 1;
        int half = blk & 1;
        int b = bk / KK_;
        const float4* pack = (const float4*)(ws + OFF_TGT_PACK) + b * NN_;
        for (int j = tid; j < NN_; j += 576) {
            u.pk[j ^ ((j >> 6) & 7)] = pack[j];              // XOR-swizzled slots
        }
        const float* xf = ws + OFF_XFORM + bk * 3;
        float x0 = xf[0], x1 = xf[1], x2 = xf[2];
        __syncthreads();

        int lg = tid >> 5;                                   // local group 0..17
        int chunk = tid & 31;
        int grp = half * 18 + lg;                            // 0..35 = ix*6+iy
        int ix = grp / 6, iy = grp % 6;
        float cx = x0 + (ix * 0.4f - 1.0f);
        float cy = x1 + (iy * 0.4f - 1.0f);
        float cxy2;
        {
#pragma clang fp contract(off)
            cxy2 = cx * cx + cy * cy;
        }
        float m2x = -2.0f * cx, m2y = -2.0f * cy;
        float aaz[6], m2z[6];
#pragma unroll
        for (int z = 0; z < 6; ++z) {
            float cz = x2 + (z * 0.4f - 1.0f);
            {
#pragma clang fp contract(off)
                aaz[z] = cxy2 + cz * cz;
            }
            m2z[z] = -2.0f * cz;
        }
        float bv[6];
        int bi[6];
#pragma unroll
        for (int z = 0; z < 6; ++z) { bv[z] = INFINITY; bi[z] = 0; }
        int base = chunk * 64;
        int sw = chunk & 7;
        for (int i = 0; i < 64; ++i) {
            int j = base + i;                                // ascending j (first-idx ties)
            float4 p = u.pk[base + (i ^ sw)];                // slot(j) for j=base+i
            float txy;
            {
#pragma clang fp contract(off)
                txy = m2x * p.x + m2y * p.y;
            }
#pragma unroll
            for (int z = 0; z < 6; ++z) {
                float d2;
                {
#pragma clang fp contract(off)
                    d2 = (aaz[z] + p.w) + (txy + m2z[z] * p.z);
                }
                if (d2 < bv[z]) { bv[z] = d2; bi[z] = j; }
            }
        }
        int* nnt = (int*)ws + OFF_NNT + bk * NC_ + grp * 6;
#pragma unroll
        for (int z = 0; z < 6; ++z) {
            unsigned long long key = ((unsigned long long)sortable_f32(bv[z]) << 32) | (unsigned)bi[z];
#pragma unroll
            for (int m = 1; m <= 16; m <<= 1) {
                unsigned long long other = __shfl_xor(key, m);
                key = other < key ? other : key;
            }
            if (chunk == 0) nnt[z] = (int)(key & 0xFFFFFFFFu);
        }
    }
    __syncthreads();

    // ---------------- Phase 2b: src grouping + dfe + max (blocks 128..255) ----
    if (blk >= BB_ * KK_) {
        int bk = blk - BB_ * KK_;
        int b = bk / KK_;
        int w = tid >> 6, lane = tid & 63;
        const float* cen = ws + OFF_CENTERS + bk * 3;
        float c0 = cen[0], c1 = cen[1], c2 = cen[2];
        float aa;
        {
#pragma clang fp contract(off)
            aa = (c0 * c0 + c1 * c1) + c2 * c2;
        }
        float m2x = -2.0f * c0, m2y = -2.0f * c1, m2z = -2.0f * c2;
        const float4* pack = (const float4*)(ws + OFF_SRC_PACK) + b * NN_;
        if (w < 8) {
            unsigned long long k4[4];
#pragma unroll
            for (int q = 0; q < 4; ++q) {
                int j = w * 256 + q * 64 + lane;
                float4 p = pack[j];
                float d2;
                {
#pragma clang fp contract(off)
                    d2 = (aa + p.w) + ((m2x * p.x + m2y * p.y) + m2z * p.z);
                }
                k4[q] = ((unsigned long long)sortable_f32(d2) << 32) | (unsigned)j;
            }
            unsigned long long m1 = merge_keep_min64(wave_sort64_asc(k4[0], lane),
                                                     wave_sort64_asc(k4[1], lane), lane);
            unsigned long long m2 = merge_keep_min64(wave_sort64_asc(k4[2], lane),
                                                     wave_sort64_asc(k4[3], lane), lane);
            u.s.runs[w * 64 + lane] = merge_keep_min64(m1, m2, lane);
        }
        __syncthreads();
#pragma unroll
        for (int lvl = 4; lvl >= 1; lvl >>= 1) {
            unsigned long long r = 0;
            if (w < lvl) r = merge_keep_min64(u.s.runs[w * 64 + lane], u.s.runs[(w + lvl) * 64 + lane], lane);
            __syncthreads();
            if (w < lvl) u.s.runs[w * 64 + lane] = r;
            __syncthreads();
        }
        const float* feats = ws + OFF_SRC_FEAT + (size_t)b * NN_ * DD_;
        unsigned long long key0 = u.s.runs[0];
        if (w < 8) {
#pragma unroll
            for (int ss = 0; ss < 4; ++ss) {
                int s = w * 4 + ss;
                unsigned long long key = u.s.runs[s];
                float dd = unsortable_f32((unsigned)(key >> 32));
                int j = (dd <= 1.0f) ? (int)(key & 0xFFFFFFFFu) : (int)(key0 & 0xFFFFFFFFu);  // R^2=1
                float4 p = pack[j];
                float r0 = p.x - c0, r1 = p.y - c1, r2 = p.z - c2;
                const float* f = feats + (size_t)j * DD_;
                float acc = b3[lane] + r0 * W3[0 * HH_ + lane] + r1 * W3[1 * HH_ + lane] + r2 * W3[2 * HH_ + lane];
#pragma unroll 8
                for (int d = 0; d < DD_; ++d) acc += f[d] * W3[(3 + d) * HH_ + lane];
                u.s.hs[s][lane] = fmaxf(acc, 0.f);
            }
        }
        __syncthreads();
        for (int idx = tid; idx < NS_ * DD_; idx += 576) {
            int s2 = idx >> 5, di = idx & 31;
            float o = b4[di];
#pragma unroll 8
            for (int t2 = 0; t2 < HH_; ++t2) o += u.s.hs[s2][t2] * W4[t2 * DD_ + di];
            u.s.outs[s2][di] = fmaxf(o, 0.f);
        }
        __syncthreads();
        if (tid < DD_) {
            float m = -INFINITY;
#pragma unroll 8
            for (int s = 0; s < NS_; ++s) m = fmaxf(m, u.s.outs[s][tid]);
            (ws + OFF_SRCDFE)[bk * DD_ + tid] = m;
        }
    }
    grid.sync();

    // ---------------- Phase 3: candidate MLP + sim + softmax + vcp (blocks 0..127) ----
    if (blk < BB_ * KK_) {
        int bk = blk;
        int b = bk / KK_;
        const float* xf = ws + OFF_XFORM + bk * 3;
        if (tid < NC_) {
            int c = tid;
            int ix = c / 36, iy = (c / 6) % 6, iz = c % 6;
            float cx = xf[0] + (ix * 0.4f - 1.0f);
            float cy = xf[1] + (iy * 0.4f - 1.0f);
            float cz = xf[2] + (iz * 0.4f - 1.0f);
            int bi = ((const int*)ws)[OFF_NNT + bk * NC_ + c];
            float4 p = ((const float4*)(ws + OFF_TGT_PACK))[b * NN_ + bi];
            float x[3 + DD_];
            x[0] = p.x - cx; x[1] = p.y - cy; x[2] = p.z - cz;
            const float* f = ws + OFF_TGT_FEAT + ((size_t)b * NN_ + bi) * DD_;
#pragma unroll
            for (int d = 0; d < DD_; ++d) x[3 + d] = f[d];
            float o[DD_];
#pragma unroll
            for (int d = 0; d < DD_; ++d) o[d] = b4[d];
            for (int tt = 0; tt < HH_; ++tt) {
                float acc = b3[tt];
#pragma unroll
                for (int cc = 0; cc < 3 + DD_; ++cc) acc += x[cc] * W3[cc * HH_ + tt];
                float ht = fmaxf(acc, 0.f);
#pragma unroll
                for (int d = 0; d < DD_; ++d) o[d] += ht * W4[tt * DD_ + d];
            }
            const float* sd = ws + OFF_SRCDFE + bk * DD_;
            float sim = 0.f;
#pragma unroll
            for (int d = 0; d < DD_; ++d) sim += fmaxf(o[d], 0.f) * sd[d];
            u.sims[c] = sim;
        }
        __syncthreads();
        if (tid < 64) {
            int lane = tid;
            float m = -INFINITY;
            for (int c = lane; c < NC_; c += 64) m = fmaxf(m, u.sims[c]);
#pragma unroll
            for (int sh = 32; sh; sh >>= 1) m = fmaxf(m, __shfl_xor(m, sh));
            float se = 0.f, v0 = 0.f, v1 = 0.f, v2 = 0.f;
            for (int c = lane; c < NC_; c += 64) {
                float e = expf(u.sims[c] - m);
                int ix = c / 36, iy = (c / 6) % 6, iz = c % 6;
                se += e;
                v0 += e * (xf[0] + (ix * 0.4f - 1.0f));
                v1 += e * (xf[1] + (iy * 0.4f - 1.0f));
                v2 += e * (xf[2] + (iz * 0.4f - 1.0f));
            }
#pragma unroll
            for (int sh = 32; sh; sh >>= 1) {
                se += __shfl_xor(se, sh);
                v0 += __shfl_xor(v0, sh);
                v1 += __shfl_xor(v1, sh);
                v2 += __shfl_xor(v2, sh);
            }
            if (lane == 0) {
                float inv = 1.0f / se;
                float* oo = out + BB_ * KK_ * CC_ + bk * 3;
                oo[0] = v0 * inv;
                oo[1] = v1 * inv;
                oo[2] = v2 * inv;
            }
        }
    }
}

// ==================== fallback path (R6 kernels, unchanged) ====================
__global__ void fe_kernel(const float* __restrict__ src, const float* __restrict__ tgt,
                          const float* __restrict__ W1, const float* __restrict__ b1,
                          const float* __restrict__ W2, const float* __restrict__ b2,
                          const float* __restrict__ Wwl, const float* __restrict__ bwl,
                          float* __restrict__ ws) {
    int tid = blockIdx.x * blockDim.x + threadIdx.x;
    if (tid >= 2 * BB_ * NN_) return;
    int cloud = tid / (BB_ * NN_);
    int r = tid - cloud * BB_ * NN_;
    int b = r / NN_, n = r % NN_;
    const float* pts = cloud ? tgt : src;
    float x[CC_];
#pragma unroll
    for (int c = 0; c < CC_; ++c) x[c] = pts[(b * CC_ + c) * NN_ + n];
    float bb;
    {
#pragma clang fp contract(off)
        bb = (x[0] * x[0] + x[1] * x[1]) + x[2] * x[2];
    }
    float4* pack = (float4*)(ws + (cloud ? OFF_TGT_PACK : OFF_SRC_PACK));
    pack[b * NN_ + n] = make_float4(x[0], x[1], x[2], bb);
    float h[HH_];
#pragma unroll
    for (int t = 0; t < HH_; ++t) {
        float s = b1[t];
#pragma unroll
        for (int c = 0; c < CC_; ++c) s += x[c] * W1[c * HH_ + t];
        h[t] = fmaxf(s, 0.f);
    }
    float* feat = ws + (cloud ? OFF_TGT_FEAT : OFF_SRC_FEAT) + (size_t)(b * NN_ + n) * DD_;
    float wsum = 0.f;
#pragma unroll 4
    for (int d = 0; d < DD_; ++d) {
        float s = b2[d];
#pragma unroll
        for (int t = 0; t < HH_; ++t) s += h[t] * W2[t * DD_ + d];
        s = fmaxf(s, 0.f);
        feat[d] = s;
        wsum += s * Wwl[d];
    }
    if (cloud == 0) (ws + OFF_W)[b * NN_ + n] = wsum + bwl[0];
}

__global__ void topk_kernel(const float* __restrict__ src, const float* __restrict__ R,
                            const float* __restrict__ t, float* __restrict__ ws,
                            float* __restrict__ out) {
    __shared__ unsigned long long runs[8 * 64];
    int b = blockIdx.x;
    int tid = threadIdx.x, w = tid >> 6, lane = tid & 63;
    const float* wv = ws + OFF_W + b * NN_;
    if (w < 8) {
        unsigned long long k4[4];
#pragma unroll
        for (int q = 0; q < 4; ++q) {
            int j = w * 256 + q * 64 + lane;
            k4[q] = ((unsigned long long)(~sortable_f32(wv[j])) << 32) | (unsigned)j;
        }
        unsigned long long m1 = merge_keep_min64(wave_sort64_asc(k4[0], lane), wave_sort64_asc(k4[1], lane), lane);
        unsigned long long m2 = merge_keep_min64(wave_sort64_asc(k4[2], lane), wave_sort64_asc(k4[3], lane), lane);
        runs[w * 64 + lane] = merge_keep_min64(m1, m2, lane);
    }
    __syncthreads();
#pragma unroll
    for (int lvl = 4; lvl >= 1; lvl >>= 1) {
        unsigned long long r = 0;
        if (w < lvl) r = merge_keep_min64(runs[w * 64 + lane], runs[(w + lvl) * 64 + lane], lane);
        __syncthreads();
        if (w < lvl) runs[w * 64 + lane] = r;
        __syncthreads();
    }
    if (tid < KK_) {
        int bi = (int)(runs[tid] & 0xFFFFFFFFu);
        float c3[3];
#pragma unroll
        for (int c = 0; c < CC_; ++c) {
            float v = src[(b * CC_ + c) * NN_ + bi];
            out[(b * KK_ + tid) * CC_ + c] = v;
            if (c < 3) c3[c] = v;
        }
        float* cen = ws + OFF_CENTERS + (b * KK_ + tid) * 3;
        cen[0] = c3[0]; cen[1] = c3[1]; cen[2] = c3[2];
        float* xf = ws + OFF_XFORM + (b * KK_ + tid) * 3;
#pragma unroll
        for (int i = 0; i < 3; ++i) {
#pragma clang fp contract(off)
            xf[i] = ((R[i * 3 + 0] * c3[0] + R[i * 3 + 1] * c3[1]) + R[i * 3 + 2] * c3[2]) + t[i];
        }
    }
}

__global__ __launch_bounds__(576) void mid_kernel(const float* __restrict__ W3, const float* __restrict__ b3,
                                                  const float* __restrict__ W4, const float* __restrict__ b4,
                                                  float* __restrict__ ws) {
    __shared__ MegaLds u;
    int blk = blockIdx.x;
    int tid = threadIdx.x;
    if (blk < 2 * BB_ * KK_) {
        int bk = blk >> 1;
        int half = blk & 1;
        int b = bk / KK_;
        const float4* pack = (const float4*)(ws + OFF_TGT_PACK) + b * NN_;
        for (int j = tid; j < NN_; j += 576) u.pk[j ^ ((j >> 6) & 7)] = pack[j];
        const float* xf = ws + OFF_XFORM + bk * 3;
        float x0 = xf[0], x1 = xf[1], x2 = xf[2];
        __syncthreads();
        int lg = tid >> 5;
        int chunk = tid & 31;
        int grp = half * 18 + lg;
        int ix = grp / 6, iy = grp % 6;
        float cx = x0 + (ix * 0.4f - 1.0f);
        float cy = x1 + (iy * 0.4f - 1.0f);
        float cxy2;
        {
#pragma clang fp contract(off)
            cxy2 = cx * cx + cy * cy;
        }
        float m2x = -2.0f * cx, m2y = -2.0f * cy;
        float aaz[6], m2z[6];
#pragma unroll
        for (int z = 0; z < 6; ++z) {
            float cz = x2 + (z * 0.4f - 1.0f);
            {
#pragma clang fp contract(off)
                aaz[z] = cxy2 + cz * cz;
            }
            m2z[z] = -2.0f * cz;
        }
        float bv[6];
        int bi[6];
#pragma unroll
        for (int z = 0; z < 6; ++z) { bv[z] = INFINITY; bi[z] = 0; }
        int base = chunk * 64;
        int sw = chunk & 7;
        for (int i = 0; i < 64; ++i) {
            int j = base + i;
            float4 p = u.pk[base + (i ^ sw)];
            float txy;
            {
#pragma clang fp contract(off)
                txy = m2x * p.x + m2y * p.y;
            }
#pragma unroll
            for (int z = 0; z < 6; ++z) {
                float d2;
                {
#pragma clang fp contract(off)
                    d2 = (aaz[z] + p.w) + (txy + m2z[z] * p.z);
                }
                if (d2 < bv[z]) { bv[z] = d2; bi[z] = j; }
            }
        }
        int* nnt = (int*)ws + OFF_NNT + bk * NC_ + grp * 6;
#pragma unroll
        for (int z = 0; z < 6; ++z) {
            unsigned long long key = ((unsigned long long)sortable_f32(bv[z]) << 32) | (unsigned)bi[z];
#pragma unroll
            for (int m = 1; m <= 16; m <<= 1) {
                unsigned long long other = __shfl_xor(key, m);
                key = other < key ? other : key;
            }
            if (chunk == 0) nnt[z] = (int)(key & 0xFFFFFFFFu);
        }
    } else {
        int bk = blk - 2 * BB_ * KK_;
        int b = bk / KK_;
        int w = tid >> 6, lane = tid & 63;
        const float* cen = ws + OFF_CENTERS + bk * 3;
        float c0 = cen[0], c1 = cen[1], c2 = cen[2];
        float aa;
        {
#pragma clang fp contract(off)
            aa = (c0 * c0 + c1 * c1) + c2 * c2;
        }
        float m2x = -2.0f * c0, m2y = -2.0f * c1, m2z = -2.0f * c2;
        const float4* pack = (const float4*)(ws + OFF_SRC_PACK) + b * NN_;
        if (w < 8) {
            unsigned long long k4[4];
#pragma unroll
            for (int q = 0; q < 4; ++q) {
                int j = w * 256 + q * 64 + lane;
                float4 p = pack[j];
                float d2;
                {
#pragma clang fp contract(off)
                    d2 = (aa + p.w) + ((m2x * p.x + m2y * p.y) + m2z * p.z);
                }
                k4[q] = ((unsigned long long)sortable_f32(d2) << 32) | (unsigned)j;
            }
            unsigned long long m1 = merge_keep_min64(wave_sort64_asc(k4[0], lane), wave_sort64_asc(k4[1], lane), lane);
            unsigned long long m2 = merge_keep_min64(wave_sort64_asc(k4[2], lane), wave_sort64_asc(k4[3], lane), lane);
            u.s.runs[w * 64 + lane] = merge_keep_min64(m1, m2, lane);
        }
        __syncthreads();
#pragma unroll
        for (int lvl = 4; lvl >= 1; lvl >>= 1) {
            unsigned long long r = 0;
            if (w < lvl) r = merge_keep_min64(u.s.runs[w * 64 + lane], u.s.runs[(w + lvl) * 64 + lane], lane);
            __syncthreads();
            if (w < lvl) u.s.runs[w * 64 + lane] = r;
            __syncthreads();
        }
        const float* feats = ws + OFF_SRC_FEAT + (size_t)b * NN_ * DD_;
        unsigned long long key0 = u.s.runs[0];
        if (w < 8) {
#pragma unroll
            for (int ss = 0; ss < 4; ++ss) {
                int s = w * 4 + ss;
                unsigned long long key = u.s.runs[s];
                float dd = unsortable_f32((unsigned)(key >> 32));
                int j = (dd <= 1.0f) ? (int)(key & 0xFFFFFFFFu) : (int)(key0 & 0xFFFFFFFFu);
                float4 p = pack[j];
                float r0 = p.x - c0, r1 = p.y - c1, r2 = p.z - c2;
                const float* f = feats + (size_t)j * DD_;
                float acc = b3[lane] + r0 * W3[0 * HH_ + lane] + r1 * W3[1 * HH_ + lane] + r2 * W3[2 * HH_ + lane];
#pragma unroll 8
                for (int d = 0; d < DD_; ++d) acc += f[d] * W3[(3 + d) * HH_ + lane];
                u.s.hs[s][lane] = fmaxf(acc, 0.f);
            }
        }
        __syncthreads();
        for (int idx = tid; idx < NS_ * DD_; idx += 576) {
            int s2 = idx >> 5, di = idx & 31;
            float o = b4[di];
#pragma unroll 8
            for (int t2 = 0; t2 < HH_; ++t2) o += u.s.hs[s2][t2] * W4[t2 * DD_ + di];
            u.s.outs[s2][di] = fmaxf(o, 0.f);
        }
        __syncthreads();
        if (tid < DD_) {
            float m = -INFINITY;
#pragma unroll 8
            for (int s = 0; s < NS_; ++s) m = fmaxf(m, u.s.outs[s][tid]);
            (ws + OFF_SRCDFE)[bk * DD_ + tid] = m;
        }
    }
}

__global__ void simvcp_kernel(const float* __restrict__ W3, const float* __restrict__ b3,
                              const float* __restrict__ W4, const float* __restrict__ b4,
                              float* __restrict__ ws, float* __restrict__ out) {
    __shared__ float sims[NC_];
    int bk = blockIdx.x;
    int b = bk / KK_;
    int tid = threadIdx.x;
    const float* xf = ws + OFF_XFORM + bk * 3;
    if (tid < NC_) {
        int c = tid;
        int ix = c / 36, iy = (c / 6) % 6, iz = c % 6;
        float cx = xf[0] + (ix * 0.4f - 1.0f);
        float cy = xf[1] + (iy * 0.4f - 1.0f);
        float cz = xf[2] + (iz * 0.4f - 1.0f);
        int bi = ((const int*)ws)[OFF_NNT + bk * NC_ + c];
        float4 p = ((const float4*)(ws + OFF_TGT_PACK))[b * NN_ + bi];
        float x[3 + DD_];
        x[0] = p.x - cx; x[1] = p.y - cy; x[2] = p.z - cz;
        const float* f = ws + OFF_TGT_FEAT + ((size_t)b * NN_ + bi) * DD_;
#pragma unroll
        for (int d = 0; d < DD_; ++d) x[3 + d] = f[d];
        float o[DD_];
#pragma unroll
        for (int d = 0; d < DD_; ++d) o[d] = b4[d];
        for (int t = 0; t < HH_; ++t) {
            float acc = b3[t];
#pragma unroll
            for (int cc = 0; cc < 3 + DD_; ++cc) acc += x[cc] * W3[cc * HH_ + t];
            float ht = fmaxf(acc, 0.f);
#pragma unroll
            for (int d = 0; d < DD_; ++d) o[d] += ht * W4[t * DD_ + d];
        }
        const float* sd = ws + OFF_SRCDFE + bk * DD_;
        float sim = 0.f;
#pragma unroll
        for (int d = 0; d < DD_; ++d) sim += fmaxf(o[d], 0.f) * sd[d];
        sims[c] = sim;
    }
    __syncthreads();
    if (tid < 64) {
        int lane = tid;
        float m = -INFINITY;
        for (int c = lane; c < NC_; c += 64) m = fmaxf(m, sims[c]);
#pragma unroll
        for (int sh = 32; sh; sh >>= 1) m = fmaxf(m, __shfl_xor(m, sh));
        float se = 0.f, v0 = 0.f, v1 = 0.f, v2 = 0.f;
        for (int c = lane; c < NC_; c += 64) {
            float e = expf(sims[c] - m);
            int ix = c / 36, iy = (c / 6) % 6, iz = c % 6;
            se += e;
            v0 += e * (xf[0] + (ix * 0.4f - 1.0f));
            v1 += e * (xf[1] + (iy * 0.4f - 1.0f));
            v2 += e * (xf[2] + (iz * 0.4f - 1.0f));
        }
#pragma unroll
        for (int sh = 32; sh; sh >>= 1) {
            se += __shfl_xor(se, sh);
            v0 += __shfl_xor(v0, sh);
            v1 += __shfl_xor(v1, sh);
            v2 += __shfl_xor(v2, sh);
        }
        if (lane == 0) {
            float inv = 1.0f / se;
            float* oo = out + BB_ * KK_ * CC_ + bk * 3;
            oo[0] = v0 * inv;
            oo[1] = v1 * inv;
            oo[2] = v2 * inv;
        }
    }
}

extern "C" void kernel_launch(void* const* d_in, const int* in_sizes, int n_in,
                              void* d_out, int out_size, void* d_ws, size_t ws_size,
                              hipStream_t stream) {
    const float* src = (const float*)d_in[0];
    const float* tgt = (const float*)d_in[1];
    const float* R   = (const float*)d_in[2];
    const float* t   = (const float*)d_in[3];
    const float* W1  = (const float*)d_in[4];
    const float* b1  = (const float*)d_in[5];
    const float* W2  = (const float*)d_in[6];
    const float* b2  = (const float*)d_in[7];
    const float* Wwl = (const float*)d_in[8];
    const float* bwl = (const float*)d_in[9];
    const float* W3  = (const float*)d_in[10];
    const float* b3  = (const float*)d_in[11];
    const float* W4  = (const float*)d_in[12];
    const float* b4  = (const float*)d_in[13];
    float* ws  = (float*)d_ws;
    float* out = (float*)d_out;

    void* args[] = {(void*)&src, (void*)&tgt, (void*)&R, (void*)&t,
                    (void*)&W1, (void*)&b1, (void*)&W2, (void*)&b2,
                    (void*)&Wwl, (void*)&bwl, (void*)&W3, (void*)&b3,
                    (void*)&W4, (void*)&b4, (void*)&ws, (void*)&out};
    hipError_t e = hipLaunchCooperativeKernel((const void*)mega_kernel,
                                              dim3(2 * BB_ * KK_), dim3(576),
                                              args, 0, stream);
    if (e != hipSuccess) {
        // fallback: R6 4-kernel chain
        fe_kernel<<<(2 * BB_ * NN_ + 127) / 128, 128, 0, stream>>>(src, tgt, W1, b1, W2, b2, Wwl, bwl, ws);
        topk_kernel<<<BB_, 576, 0, stream>>>(src, R, t, ws, out);
        mid_kernel<<<2 * BB_ * KK_ + BB_ * KK_, 576, 0, stream>>>(W3, b3, W4, b4, ws);
        simvcp_kernel<<<BB_ * KK_, 256, 0, stream>>>(W3, b3, W4, b4, ws, out);
    }
}

// Round 8
// 149.710 us; speedup vs baseline: 1.1002x; 1.1002x over previous
//
#include <hip/hip_runtime.h>
#include <math.h>

// Problem constants
#define BB_ 2      // batch
#define CC_ 6      // channels
#define NN_ 2048   // points
#define KK_ 64     // keypoints
#define NS_ 32     // neighbors
#define DD_ 32     // feat dim
#define NC_ 216    // candidate grid (6^3)
#define HH_ 64     // hidden dim
#define NBLK_ 256  // mega-kernel grid

// Workspace layout (in floats)
#define OFF_SRC_PACK 0                    // B*N float4 = 16384 floats
#define OFF_TGT_PACK 16384                // 16384
#define OFF_SRC_FEAT 32768                // B*N*D = 131072
#define OFF_TGT_FEAT 163840               // 131072
#define OFF_W        294912               // B*N = 4096
#define OFF_CENTERS  299008               // B*K*3 = 384
#define OFF_XFORM    299392               // 384
#define OFF_SRCDFE   299776               // B*K*D = 4096
#define OFF_NNT      303872               // B*K*NC ints = 27648
#define OFF_BAR      331520               // 1 uint barrier counter

// Order-preserving bijection float -> uint32 (ascending)
__device__ __forceinline__ unsigned sortable_f32(float f) {
    unsigned u = __float_as_uint(f);
    return (u & 0x80000000u) ? ~u : (u | 0x80000000u);
}
__device__ __forceinline__ float unsortable_f32(unsigned s) {
    unsigned u = (s & 0x80000000u) ? (s ^ 0x80000000u) : ~s;
    return __uint_as_float(u);
}

// Full ascending bitonic sort of 64 u64 keys across the 64 lanes of a wave.
__device__ __forceinline__ unsigned long long wave_sort64_asc(unsigned long long key, int lane) {
#pragma unroll
    for (int k = 2; k <= 64; k <<= 1) {
#pragma unroll
        for (int j = k >> 1; j > 0; j >>= 1) {
            unsigned long long other = __shfl_xor(key, j);
            bool lower = (lane & j) == 0;
            bool asc = (lane & k) == 0;
            bool takemin = (lower == asc);
            unsigned long long mn = key < other ? key : other;
            unsigned long long mx = key < other ? other : key;
            key = takemin ? mn : mx;
        }
    }
    return key;
}

// Two ascending sorted 64-runs -> smallest 64 of the union, ascending.
__device__ __forceinline__ unsigned long long merge_keep_min64(unsigned long long a, unsigned long long b, int lane) {
    unsigned long long br = __shfl(b, 63 - lane);
    unsigned long long m = a < br ? a : br;
#pragma unroll
    for (int j = 32; j > 0; j >>= 1) {
        unsigned long long other = __shfl_xor(m, j);
        bool lower = (lane & j) == 0;
        unsigned long long mn = m < other ? m : other;
        unsigned long long mx = m < other ? other : m;
        m = lower ? mn : mx;
    }
    return m;
}

// Lightweight device-scope grid barrier. Cooperative launch guarantees all
// NBLK_ blocks co-resident -> no deadlock. Counter zeroed by hipMemsetAsync
// at the head of each kernel_launch (captured in the graph).
__device__ __forceinline__ void grid_bar(unsigned* bar, unsigned target, int tid) {
    __syncthreads();
    if (tid == 0) {
        __threadfence();                       // agent-scope release
        atomicAdd(bar, 1u);                    // device-scope by default
        while (__hip_atomic_load(bar, __ATOMIC_RELAXED, __HIP_MEMORY_SCOPE_AGENT) < target) {
            __builtin_amdgcn_s_sleep(2);
        }
        __threadfence();                       // acquire
    }
    __syncthreads();
}

struct MegaLds {
    union {
        float4 pk[NN_];                                      // cand role: 32 KB
        struct {
            unsigned long long runs[8 * 64];                 // 4 KB
            float hs[NS_][HH_];                              // 8 KB
            float outs[NS_][DD_];                            // 4 KB
        } s;
        float sims[NC_];
    };
};

// ==================== fused single-launch kernel ====================
__global__ __launch_bounds__(576) void mega_kernel(
        const float* __restrict__ src, const float* __restrict__ tgt,
        const float* __restrict__ R, const float* __restrict__ t,
        const float* __restrict__ W1, const float* __restrict__ b1,
        const float* __restrict__ W2, const float* __restrict__ b2,
        const float* __restrict__ Wwl, const float* __restrict__ bwl,
        const float* __restrict__ W3, const float* __restrict__ b3,
        const float* __restrict__ W4, const float* __restrict__ b4,
        float* __restrict__ ws, float* __restrict__ out) {
    __shared__ MegaLds u;
    int blk = blockIdx.x;
    int tid = threadIdx.x;                                   // 0..575
    unsigned* bar = (unsigned*)(ws + OFF_BAR);

    // ---------------- Phase 0: feature extraction (32 points per block) ------
    if (tid < 32) {
        int g = blk * 32 + tid;                              // 256*32 = 8192 = 2*B*N
        int cloud = g / (BB_ * NN_);
        int r = g - cloud * BB_ * NN_;
        int b = r / NN_, n = r % NN_;
        const float* pts = cloud ? tgt : src;
        float x[CC_];
#pragma unroll
        for (int c = 0; c < CC_; ++c) x[c] = pts[(b * CC_ + c) * NN_ + n];
        float bb;
        {
#pragma clang fp contract(off)
            bb = (x[0] * x[0] + x[1] * x[1]) + x[2] * x[2];
        }
        float4* pack = (float4*)(ws + (cloud ? OFF_TGT_PACK : OFF_SRC_PACK));
        pack[b * NN_ + n] = make_float4(x[0], x[1], x[2], bb);
        float h[HH_];
#pragma unroll
        for (int tt = 0; tt < HH_; ++tt) {
            float s = b1[tt];
#pragma unroll
            for (int c = 0; c < CC_; ++c) s += x[c] * W1[c * HH_ + tt];
            h[tt] = fmaxf(s, 0.f);
        }
        float* feat = ws + (cloud ? OFF_TGT_FEAT : OFF_SRC_FEAT) + (size_t)(b * NN_ + n) * DD_;
        float wsum = 0.f;
#pragma unroll 4
        for (int d = 0; d < DD_; ++d) {
            float s = b2[d];
#pragma unroll
            for (int tt = 0; tt < HH_; ++tt) s += h[tt] * W2[tt * DD_ + d];
            s = fmaxf(s, 0.f);
            feat[d] = s;
            wsum += s * Wwl[d];
        }
        if (cloud == 0) (ws + OFF_W)[b * NN_ + n] = wsum + bwl[0];
    }
    grid_bar(bar, 1 * NBLK_, tid);

    // ---------------- Phase 1: top-K keypoints (blocks 0..1) ----------------
    if (blk < BB_) {
        int b = blk;
        int w = tid >> 6, lane = tid & 63;
        const float* wv = ws + OFF_W + b * NN_;
        if (w < 8) {
            unsigned long long k4[4];
#pragma unroll
            for (int q = 0; q < 4; ++q) {
                int j = w * 256 + q * 64 + lane;
                k4[q] = ((unsigned long long)(~sortable_f32(wv[j])) << 32) | (unsigned)j;
            }
            unsigned long long m1 = merge_keep_min64(wave_sort64_asc(k4[0], lane),
                                                     wave_sort64_asc(k4[1], lane), lane);
            unsigned long long m2 = merge_keep_min64(wave_sort64_asc(k4[2], lane),
                                                     wave_sort64_asc(k4[3], lane), lane);
            u.s.runs[w * 64 + lane] = merge_keep_min64(m1, m2, lane);
        }
        __syncthreads();
#pragma unroll
        for (int lvl = 4; lvl >= 1; lvl >>= 1) {
            unsigned long long r = 0;
            if (w < lvl) r = merge_keep_min64(u.s.runs[w * 64 + lane], u.s.runs[(w + lvl) * 64 + lane], lane);
            __syncthreads();
            if (w < lvl) u.s.runs[w * 64 + lane] = r;
            __syncthreads();
        }
        if (tid < KK_) {
            int bi = (int)(u.s.runs[tid] & 0xFFFFFFFFu);
            float c3[3];
#pragma unroll
            for (int c = 0; c < CC_; ++c) {
                float v = src[(b * CC_ + c) * NN_ + bi];
                out[(b * KK_ + tid) * CC_ + c] = v;
                if (c < 3) c3[c] = v;
            }
            float* cen = ws + OFF_CENTERS + (b * KK_ + tid) * 3;
            cen[0] = c3[0]; cen[1] = c3[1]; cen[2] = c3[2];
            float* xf = ws + OFF_XFORM + (b * KK_ + tid) * 3;
#pragma unroll
            for (int i = 0; i < 3; ++i) {
#pragma clang fp contract(off)
                xf[i] = ((R[i * 3 + 0] * c3[0] + R[i * 3 + 1] * c3[1]) + R[i * 3 + 2] * c3[2]) + t[i];
            }
        }
    }
    grid_bar(bar, 2 * NBLK_, tid);

    // ---------------- Phase 2a: candidate NN (all 256 blocks) ----------------
    {
        int bk = blk >> 1;
        int half = blk & 1;
        int b = bk / KK_;
        const float4* pack = (const float4*)(ws + OFF_TGT_PACK) + b * NN_;
        for (int j = tid; j < NN_; j += 576) {
            u.pk[j ^ ((j >> 6) & 7)] = pack[j];              // XOR-swizzled slots
        }
        const float* xf = ws + OFF_XFORM + bk * 3;
        float x0 = xf[0], x1 = xf[1], x2 = xf[2];
        __syncthreads();

        int lg = tid >> 5;                                   // local group 0..17
        int chunk = tid & 31;
        int grp = half * 18 + lg;                            // 0..35 = ix*6+iy
        int ix = grp / 6, iy = grp % 6;
        float cx = x0 + (ix * 0.4f - 1.0f);
        float cy = x1 + (iy * 0.4f - 1.0f);
        float cxy2;
        {
#pragma clang fp contract(off)
            cxy2 = cx * cx + cy * cy;
        }
        float m2x = -2.0f * cx, m2y = -2.0f * cy;
        float aaz[6], m2z[6];
#pragma unroll
        for (int z = 0; z < 6; ++z) {
            float cz = x2 + (z * 0.4f - 1.0f);
            {
#pragma clang fp contract(off)
                aaz[z] = cxy2 + cz * cz;
            }
            m2z[z] = -2.0f * cz;
        }
        float bv[6];
        int bi[6];
#pragma unroll
        for (int z = 0; z < 6; ++z) { bv[z] = INFINITY; bi[z] = 0; }
        int base = chunk * 64;
        int sw = chunk & 7;
        for (int i = 0; i < 64; ++i) {
            int j = base + i;                                // ascending j (first-idx ties)
            float4 p = u.pk[base + (i ^ sw)];                // slot(j) for j=base+i
            float txy;
            {
#pragma clang fp contract(off)
                txy = m2x * p.x + m2y * p.y;
            }
#pragma unroll
            for (int z = 0; z < 6; ++z) {
                float d2;
                {
#pragma clang fp contract(off)
                    d2 = (aaz[z] + p.w) + (txy + m2z[z] * p.z);
                }
                if (d2 < bv[z]) { bv[z] = d2; bi[z] = j; }
            }
        }
        int* nnt = (int*)ws + OFF_NNT + bk * NC_ + grp * 6;
#pragma unroll
        for (int z = 0; z < 6; ++z) {
            unsigned long long key = ((unsigned long long)sortable_f32(bv[z]) << 32) | (unsigned)bi[z];
#pragma unroll
            for (int m = 1; m <= 16; m <<= 1) {
                unsigned long long other = __shfl_xor(key, m);
                key = other < key ? other : key;
            }
            if (chunk == 0) nnt[z] = (int)(key & 0xFFFFFFFFu);
        }
    }
    __syncthreads();

    // ---------------- Phase 2b: src grouping + dfe + max (blocks 128..255) ----
    if (blk >= BB_ * KK_) {
        int bk = blk - BB_ * KK_;
        int b = bk / KK_;
        int w = tid >> 6, lane = tid & 63;
        const float* cen = ws + OFF_CENTERS + bk * 3;
        float c0 = cen[0], c1 = cen[1], c2 = cen[2];
        float aa;
        {
#pragma clang fp contract(off)
            aa = (c0 * c0 + c1 * c1) + c2 * c2;
        }
        float m2x = -2.0f * c0, m2y = -2.0f * c1, m2z = -2.0f * c2;
        const float4* pack = (const float4*)(ws + OFF_SRC_PACK) + b * NN_;
        if (w < 8) {
            unsigned long long k4[4];
#pragma unroll
            for (int q = 0; q < 4; ++q) {
                int j = w * 256 + q * 64 + lane;
                float4 p = pack[j];
                float d2;
                {
#pragma clang fp contract(off)
                    d2 = (aa + p.w) + ((m2x * p.x + m2y * p.y) + m2z * p.z);
                }
                k4[q] = ((unsigned long long)sortable_f32(d2) << 32) | (unsigned)j;
            }
            unsigned long long m1 = merge_keep_min64(wave_sort64_asc(k4[0], lane),
                                                     wave_sort64_asc(k4[1], lane), lane);
            unsigned long long m2 = merge_keep_min64(wave_sort64_asc(k4[2], lane),
                                                     wave_sort64_asc(k4[3], lane), lane);
            u.s.runs[w * 64 + lane] = merge_keep_min64(m1, m2, lane);
        }
        __syncthreads();
#pragma unroll
        for (int lvl = 4; lvl >= 1; lvl >>= 1) {
            unsigned long long r = 0;
            if (w < lvl) r = merge_keep_min64(u.s.runs[w * 64 + lane], u.s.runs[(w + lvl) * 64 + lane], lane);
            __syncthreads();
            if (w < lvl) u.s.runs[w * 64 + lane] = r;
            __syncthreads();
        }
        const float* feats = ws + OFF_SRC_FEAT + (size_t)b * NN_ * DD_;
        unsigned long long key0 = u.s.runs[0];
        if (w < 8) {
#pragma unroll
            for (int ss = 0; ss < 4; ++ss) {
                int s = w * 4 + ss;
                unsigned long long key = u.s.runs[s];
                float dd = unsortable_f32((unsigned)(key >> 32));
                int j = (dd <= 1.0f) ? (int)(key & 0xFFFFFFFFu) : (int)(key0 & 0xFFFFFFFFu);  // R^2=1
                float4 p = pack[j];
                float r0 = p.x - c0, r1 = p.y - c1, r2 = p.z - c2;
                const float* f = feats + (size_t)j * DD_;
                float acc = b3[lane] + r0 * W3[0 * HH_ + lane] + r1 * W3[1 * HH_ + lane] + r2 * W3[2 * HH_ + lane];
#pragma unroll 8
                for (int d = 0; d < DD_; ++d) acc += f[d] * W3[(3 + d) * HH_ + lane];
                u.s.hs[s][lane] = fmaxf(acc, 0.f);
            }
        }
        __syncthreads();
        for (int idx = tid; idx < NS_ * DD_; idx += 576) {
            int s2 = idx >> 5, di = idx & 31;
            float o = b4[di];
#pragma unroll 8
            for (int t2 = 0; t2 < HH_; ++t2) o += u.s.hs[s2][t2] * W4[t2 * DD_ + di];
            u.s.outs[s2][di] = fmaxf(o, 0.f);
        }
        __syncthreads();
        if (tid < DD_) {
            float m = -INFINITY;
#pragma unroll 8
            for (int s = 0; s < NS_; ++s) m = fmaxf(m, u.s.outs[s][tid]);
            (ws + OFF_SRCDFE)[bk * DD_ + tid] = m;
        }
    }
    grid_bar(bar, 3 * NBLK_, tid);

    // ---------------- Phase 3: candidate MLP + sim + softmax + vcp (blocks 0..127) ----
    if (blk < BB_ * KK_) {
        int bk = blk;
        int b = bk / KK_;
        const float* xf = ws + OFF_XFORM + bk * 3;
        if (tid < NC_) {
            int c = tid;
            int ix = c / 36, iy = (c / 6) % 6, iz = c % 6;
            float cx = xf[0] + (ix * 0.4f - 1.0f);
            float cy = xf[1] + (iy * 0.4f - 1.0f);
            float cz = xf[2] + (iz * 0.4f - 1.0f);
            int bi = ((const int*)ws)[OFF_NNT + bk * NC_ + c];
            float4 p = ((const float4*)(ws + OFF_TGT_PACK))[b * NN_ + bi];
            float x[3 + DD_];
            x[0] = p.x - cx; x[1] = p.y - cy; x[2] = p.z - cz;
            const float* f = ws + OFF_TGT_FEAT + ((size_t)b * NN_ + bi) * DD_;
#pragma unroll
            for (int d = 0; d < DD_; ++d) x[3 + d] = f[d];
            float o[DD_];
#pragma unroll
            for (int d = 0; d < DD_; ++d) o[d] = b4[d];
            for (int tt = 0; tt < HH_; ++tt) {
                float acc = b3[tt];
#pragma unroll
                for (int cc = 0; cc < 3 + DD_; ++cc) acc += x[cc] * W3[cc * HH_ + tt];
                float ht = fmaxf(acc, 0.f);
#pragma unroll
                for (int d = 0; d < DD_; ++d) o[d] += ht * W4[tt * DD_ + d];
            }
            const float* sd = ws + OFF_SRCDFE + bk * DD_;
            float sim = 0.f;
#pragma unroll
            for (int d = 0; d < DD_; ++d) sim += fmaxf(o[d], 0.f) * sd[d];
            u.sims[c] = sim;
        }
        __syncthreads();
        if (tid < 64) {
            int lane = tid;
            float m = -INFINITY;
            for (int c = lane; c < NC_; c += 64) m = fmaxf(m, u.sims[c]);
#pragma unroll
            for (int sh = 32; sh; sh >>= 1) m = fmaxf(m, __shfl_xor(m, sh));
            float se = 0.f, v0 = 0.f, v1 = 0.f, v2 = 0.f;
            for (int c = lane; c < NC_; c += 64) {
                float e = expf(u.sims[c] - m);
                int ix = c / 36, iy = (c / 6) % 6, iz = c % 6;
                se += e;
                v0 += e * (xf[0] + (ix * 0.4f - 1.0f));
                v1 += e * (xf[1] + (iy * 0.4f - 1.0f));
                v2 += e * (xf[2] + (iz * 0.4f - 1.0f));
            }
#pragma unroll
            for (int sh = 32; sh; sh >>= 1) {
                se += __shfl_xor(se, sh);
                v0 += __shfl_xor(v0, sh);
                v1 += __shfl_xor(v1, sh);
                v2 += __shfl_xor(v2, sh);
            }
            if (lane == 0) {
                float inv = 1.0f / se;
                float* oo = out + BB_ * KK_ * CC_ + bk * 3;
                oo[0] = v0 * inv;
                oo[1] = v1 * inv;
                oo[2] = v2 * inv;
            }
        }
    }
}

// ==================== fallback path (R6 kernels) ====================
__global__ void fe_kernel(const float* __restrict__ src, const float* __restrict__ tgt,
                          const float* __restrict__ W1, const float* __restrict__ b1,
                          const float* __restrict__ W2, const float* __restrict__ b2,
                          const float* __restrict__ Wwl, const float* __restrict__ bwl,
                          float* __restrict__ ws) {
    int tid = blockIdx.x * blockDim.x + threadIdx.x;
    if (tid >= 2 * BB_ * NN_) return;
    int cloud = tid / (BB_ * NN_);
    int r = tid - cloud * BB_ * NN_;
    int b = r / NN_, n = r % NN_;
    const float* pts = cloud ? tgt : src;
    float x[CC_];
#pragma unroll
    for (int c = 0; c < CC_; ++c) x[c] = pts[(b * CC_ + c) * NN_ + n];
    float bb;
    {
#pragma clang fp contract(off)
        bb = (x[0] * x[0] + x[1] * x[1]) + x[2] * x[2];
    }
    float4* pack = (float4*)(ws + (cloud ? OFF_TGT_PACK : OFF_SRC_PACK));
    pack[b * NN_ + n] = make_float4(x[0], x[1], x[2], bb);
    float h[HH_];
#pragma unroll
    for (int t = 0; t < HH_; ++t) {
        float s = b1[t];
#pragma unroll
        for (int c = 0; c < CC_; ++c) s += x[c] * W1[c * HH_ + t];
        h[t] = fmaxf(s, 0.f);
    }
    float* feat = ws + (cloud ? OFF_TGT_FEAT : OFF_SRC_FEAT) + (size_t)(b * NN_ + n) * DD_;
    float wsum = 0.f;
#pragma unroll 4
    for (int d = 0; d < DD_; ++d) {
        float s = b2[d];
#pragma unroll
        for (int t = 0; t < HH_; ++t) s += h[t] * W2[t * DD_ + d];
        s = fmaxf(s, 0.f);
        feat[d] = s;
        wsum += s * Wwl[d];
    }
    if (cloud == 0) (ws + OFF_W)[b * NN_ + n] = wsum + bwl[0];
}

__global__ void topk_kernel(const float* __restrict__ src, const float* __restrict__ R,
                            const float* __restrict__ t, float* __restrict__ ws,
                            float* __restrict__ out) {
    __shared__ unsigned long long runs[8 * 64];
    int b = blockIdx.x;
    int tid = threadIdx.x, w = tid >> 6, lane = tid & 63;
    const float* wv = ws + OFF_W + b * NN_;
    if (w < 8) {
        unsigned long long k4[4];
#pragma unroll
        for (int q = 0; q < 4; ++q) {
            int j = w * 256 + q * 64 + lane;
            k4[q] = ((unsigned long long)(~sortable_f32(wv[j])) << 32) | (unsigned)j;
        }
        unsigned long long m1 = merge_keep_min64(wave_sort64_asc(k4[0], lane), wave_sort64_asc(k4[1], lane), lane);
        unsigned long long m2 = merge_keep_min64(wave_sort64_asc(k4[2], lane), wave_sort64_asc(k4[3], lane), lane);
        runs[w * 64 + lane] = merge_keep_min64(m1, m2, lane);
    }
    __syncthreads();
#pragma unroll
    for (int lvl = 4; lvl >= 1; lvl >>= 1) {
        unsigned long long r = 0;
        if (w < lvl) r = merge_keep_min64(runs[w * 64 + lane], runs[(w + lvl) * 64 + lane], lane);
        __syncthreads();
        if (w < lvl) runs[w * 64 + lane] = r;
        __syncthreads();
    }
    if (tid < KK_) {
        int bi = (int)(runs[tid] & 0xFFFFFFFFu);
        float c3[3];
#pragma unroll
        for (int c = 0; c < CC_; ++c) {
            float v = src[(b * CC_ + c) * NN_ + bi];
            out[(b * KK_ + tid) * CC_ + c] = v;
            if (c < 3) c3[c] = v;
        }
        float* cen = ws + OFF_CENTERS + (b * KK_ + tid) * 3;
        cen[0] = c3[0]; cen[1] = c3[1]; cen[2] = c3[2];
        float* xf = ws + OFF_XFORM + (b * KK_ + tid) * 3;
#pragma unroll
        for (int i = 0; i < 3; ++i) {
#pragma clang fp contract(off)
            xf[i] = ((R[i * 3 + 0] * c3[0] + R[i * 3 + 1] * c3[1]) + R[i * 3 + 2] * c3[2]) + t[i];
        }
    }
}

__global__ __launch_bounds__(576) void mid_kernel(const float* __restrict__ W3, const float* __restrict__ b3,
                                                  const float* __restrict__ W4, const float* __restrict__ b4,
                                                  float* __restrict__ ws) {
    __shared__ MegaLds u;
    int blk = blockIdx.x;
    int tid = threadIdx.x;
    if (blk < 2 * BB_ * KK_) {
        int bk = blk >> 1;
        int half = blk & 1;
        int b = bk / KK_;
        const float4* pack = (const float4*)(ws + OFF_TGT_PACK) + b * NN_;
        for (int j = tid; j < NN_; j += 576) u.pk[j ^ ((j >> 6) & 7)] = pack[j];
        const float* xf = ws + OFF_XFORM + bk * 3;
        float x0 = xf[0], x1 = xf[1], x2 = xf[2];
        __syncthreads();
        int lg = tid >> 5;
        int chunk = tid & 31;
        int grp = half * 18 + lg;
        int ix = grp / 6, iy = grp % 6;
        float cx = x0 + (ix * 0.4f - 1.0f);
        float cy = x1 + (iy * 0.4f - 1.0f);
        float cxy2;
        {
#pragma clang fp contract(off)
            cxy2 = cx * cx + cy * cy;
        }
        float m2x = -2.0f * cx, m2y = -2.0f * cy;
        float aaz[6], m2z[6];
#pragma unroll
        for (int z = 0; z < 6; ++z) {
            float cz = x2 + (z * 0.4f - 1.0f);
            {
#pragma clang fp contract(off)
                aaz[z] = cxy2 + cz * cz;
            }
            m2z[z] = -2.0f * cz;
        }
        float bv[6];
        int bi[6];
#pragma unroll
        for (int z = 0; z < 6; ++z) { bv[z] = INFINITY; bi[z] = 0; }
        int base = chunk * 64;
        int sw = chunk & 7;
        for (int i = 0; i < 64; ++i) {
            int j = base + i;
            float4 p = u.pk[base + (i ^ sw)];
            float txy;
            {
#pragma clang fp contract(off)
                txy = m2x * p.x + m2y * p.y;
            }
#pragma unroll
            for (int z = 0; z < 6; ++z) {
                float d2;
                {
#pragma clang fp contract(off)
                    d2 = (aaz[z] + p.w) + (txy + m2z[z] * p.z);
                }
                if (d2 < bv[z]) { bv[z] = d2; bi[z] = j; }
            }
        }
        int* nnt = (int*)ws + OFF_NNT + bk * NC_ + grp * 6;
#pragma unroll
        for (int z = 0; z < 6; ++z) {
            unsigned long long key = ((unsigned long long)sortable_f32(bv[z]) << 32) | (unsigned)bi[z];
#pragma unroll
            for (int m = 1; m <= 16; m <<= 1) {
                unsigned long long other = __shfl_xor(key, m);
                key = other < key ? other : key;
            }
            if (chunk == 0) nnt[z] = (int)(key & 0xFFFFFFFFu);
        }
    } else {
        int bk = blk - 2 * BB_ * KK_;
        int b = bk / KK_;
        int w = tid >> 6, lane = tid & 63;
        const float* cen = ws + OFF_CENTERS + bk * 3;
        float c0 = cen[0], c1 = cen[1], c2 = cen[2];
        float aa;
        {
#pragma clang fp contract(off)
            aa = (c0 * c0 + c1 * c1) + c2 * c2;
        }
        float m2x = -2.0f * c0, m2y = -2.0f * c1, m2z = -2.0f * c2;
        const float4* pack = (const float4*)(ws + OFF_SRC_PACK) + b * NN_;
        if (w < 8) {
            unsigned long long k4[4];
#pragma unroll
            for (int q = 0; q < 4; ++q) {
                int j = w * 256 + q * 64 + lane;
                float4 p = pack[j];
                float d2;
                {
#pragma clang fp contract(off)
                    d2 = (aa + p.w) + ((m2x * p.x + m2y * p.y) + m2z * p.z);
                }
                k4[q] = ((unsigned long long)sortable_f32(d2) << 32) | (unsigned)j;
            }
            unsigned long long m1 = merge_keep_min64(wave_sort64_asc(k4[0], lane), wave_sort64_asc(k4[1], lane), lane);
            unsigned long long m2 = merge_keep_min64(wave_sort64_asc(k4[2], lane), wave_sort64_asc(k4[3], lane), lane);
            u.s.runs[w * 64 + lane] = merge_keep_min64(m1, m2, lane);
        }
        __syncthreads();
#pragma unroll
        for (int lvl = 4; lvl >= 1; lvl >>= 1) {
            unsigned long long r = 0;
            if (w < lvl) r = merge_keep_min64(u.s.runs[w * 64 + lane], u.s.runs[(w + lvl) * 64 + lane], lane);
            __syncthreads();
            if (w < lvl) u.s.runs[w * 64 + lane] = r;
            __syncthreads();
        }
        const float* feats = ws + OFF_SRC_FEAT + (size_t)b * NN_ * DD_;
        unsigned long long key0 = u.s.runs[0];
        if (w < 8) {
#pragma unroll
            for (int ss = 0; ss < 4; ++ss) {
                int s = w * 4 + ss;
                unsigned long long key = u.s.runs[s];
                float dd = unsortable_f32((unsigned)(key >> 32));
                int j = (dd <= 1.0f) ? (int)(key & 0xFFFFFFFFu) : (int)(key0 & 0xFFFFFFFFu);
                float4 p = pack[j];
                float r0 = p.x - c0, r1 = p.y - c1, r2 = p.z - c2;
                const float* f = feats + (size_t)j * DD_;
                float acc = b3[lane] + r0 * W3[0 * HH_ + lane] + r1 * W3[1 * HH_ + lane] + r2 * W3[2 * HH_ + lane];
#pragma unroll 8
                for (int d = 0; d < DD_; ++d) acc += f[d] * W3[(3 + d) * HH_ + lane];
                u.s.hs[s][lane] = fmaxf(acc, 0.f);
            }
        }
        __syncthreads();
        for (int idx = tid; idx < NS_ * DD_; idx += 576) {
            int s2 = idx >> 5, di = idx & 31;
            float o = b4[di];
#pragma unroll 8
            for (int t2 = 0; t2 < HH_; ++t2) o += u.s.hs[s2][t2] * W4[t2 * DD_ + di];
            u.s.outs[s2][di] = fmaxf(o, 0.f);
        }
        __syncthreads();
        if (tid < DD_) {
            float m = -INFINITY;
#pragma unroll 8
            for (int s = 0; s < NS_; ++s) m = fmaxf(m, u.s.outs[s][tid]);
            (ws + OFF_SRCDFE)[bk * DD_ + tid] = m;
        }
    }
}

__global__ void simvcp_kernel(const float* __restrict__ W3, const float* __restrict__ b3,
                              const float* __restrict__ W4, const float* __restrict__ b4,
                              float* __restrict__ ws, float* __restrict__ out) {
    __shared__ float sims[NC_];
    int bk = blockIdx.x;
    int b = bk / KK_;
    int tid = threadIdx.x;
    const float* xf = ws + OFF_XFORM + bk * 3;
    if (tid < NC_) {
        int c = tid;
        int ix = c / 36, iy = (c / 6) % 6, iz = c % 6;
        float cx = xf[0] + (ix * 0.4f - 1.0f);
        float cy = xf[1] + (iy * 0.4f - 1.0f);
        float cz = xf[2] + (iz * 0.4f - 1.0f);
        int bi = ((const int*)ws)[OFF_NNT + bk * NC_ + c];
        float4 p = ((const float4*)(ws + OFF_TGT_PACK))[b * NN_ + bi];
        float x[3 + DD_];
        x[0] = p.x - cx; x[1] = p.y - cy; x[2] = p.z - cz;
        const float* f = ws + OFF_TGT_FEAT + ((size_t)b * NN_ + bi) * DD_;
#pragma unroll
        for (int d = 0; d < DD_; ++d) x[3 + d] = f[d];
        float o[DD_];
#pragma unroll
        for (int d = 0; d < DD_; ++d) o[d] = b4[d];
        for (int t = 0; t < HH_; ++t) {
            float acc = b3[t];
#pragma unroll
            for (int cc = 0; cc < 3 + DD_; ++cc) acc += x[cc] * W3[cc * HH_ + t];
            float ht = fmaxf(acc, 0.f);
#pragma unroll
            for (int d = 0; d < DD_; ++d) o[d] += ht * W4[t * DD_ + d];
        }
        const float* sd = ws + OFF_SRCDFE + bk * DD_;
        float sim = 0.f;
#pragma unroll
        for (int d = 0; d < DD_; ++d) sim += fmaxf(o[d], 0.f) * sd[d];
        sims[c] = sim;
    }
    __syncthreads();
    if (tid < 64) {
        int lane = tid;
        float m = -INFINITY;
        for (int c = lane; c < NC_; c += 64) m = fmaxf(m, sims[c]);
#pragma unroll
        for (int sh = 32; sh; sh >>= 1) m = fmaxf(m, __shfl_xor(m, sh));
        float se = 0.f, v0 = 0.f, v1 = 0.f, v2 = 0.f;
        for (int c = lane; c < NC_; c += 64) {
            float e = expf(sims[c] - m);
            int ix = c / 36, iy = (c / 6) % 6, iz = c % 6;
            se += e;
            v0 += e * (xf[0] + (ix * 0.4f - 1.0f));
            v1 += e * (xf[1] + (iy * 0.4f - 1.0f));
            v2 += e * (xf[2] + (iz * 0.4f - 1.0f));
        }
#pragma unroll
        for (int sh = 32; sh; sh >>= 1) {
            se += __shfl_xor(se, sh);
            v0 += __shfl_xor(v0, sh);
            v1 += __shfl_xor(v1, sh);
            v2 += __shfl_xor(v2, sh);
        }
        if (lane == 0) {
            float inv = 1.0f / se;
            float* oo = out + BB_ * KK_ * CC_ + bk * 3;
            oo[0] = v0 * inv;
            oo[1] = v1 * inv;
            oo[2] = v2 * inv;
        }
    }
}

extern "C" void kernel_launch(void* const* d_in, const int* in_sizes, int n_in,
                              void* d_out, int out_size, void* d_ws, size_t ws_size,
                              hipStream_t stream) {
    const float* src = (const float*)d_in[0];
    const float* tgt = (const float*)d_in[1];
    const float* R   = (const float*)d_in[2];
    const float* t   = (const float*)d_in[3];
    const float* W1  = (const float*)d_in[4];
    const float* b1  = (const float*)d_in[5];
    const float* W2  = (const float*)d_in[6];
    const float* b2  = (const float*)d_in[7];
    const float* Wwl = (const float*)d_in[8];
    const float* bwl = (const float*)d_in[9];
    const float* W3  = (const float*)d_in[10];
    const float* b3  = (const float*)d_in[11];
    const float* W4  = (const float*)d_in[12];
    const float* b4  = (const float*)d_in[13];
    float* ws  = (float*)d_ws;
    float* out = (float*)d_out;

    // zero the grid-barrier counter (captured as a graph node, runs every replay)
    hipMemsetAsync(ws + OFF_BAR, 0, sizeof(unsigned), stream);

    void* args[] = {(void*)&src, (void*)&tgt, (void*)&R, (void*)&t,
                    (void*)&W1, (void*)&b1, (void*)&W2, (void*)&b2,
                    (void*)&Wwl, (void*)&bwl, (void*)&W3, (void*)&b3,
                    (void*)&W4, (void*)&b4, (void*)&ws, (void*)&out};
    hipError_t e = hipLaunchCooperativeKernel((const void*)mega_kernel,
                                              dim3(NBLK_), dim3(576),
                                              args, 0, stream);
    if (e != hipSuccess) {
        // fallback: R6 4-kernel chain
        fe_kernel<<<(2 * BB_ * NN_ + 127) / 128, 128, 0, stream>>>(src, tgt, W1, b1, W2, b2, Wwl, bwl, ws);
        topk_kernel<<<BB_, 576, 0, stream>>>(src, R, t, ws, out);
        mid_kernel<<<2 * BB_ * KK_ + BB_ * KK_, 576, 0, stream>>>(W3, b3, W4, b4, ws);
        simvcp_kernel<<<BB_ * KK_, 256, 0, stream>>>(W3, b3, W4, b4, ws, out);
    }
}

// Round 9
// 137.960 us; speedup vs baseline: 1.1939x; 1.0852x over previous
//
#include <hip/hip_runtime.h>
#include <math.h>

// Problem constants
#define BB_ 2      // batch
#define CC_ 6      // channels
#define NN_ 2048   // points
#define KK_ 64     // keypoints
#define NS_ 32     // neighbors
#define DD_ 32     // feat dim
#define NC_ 216    // candidate grid (6^3)
#define HH_ 64     // hidden dim
#define NBLK_ 128  // one block per (batch, keypoint)

// Workspace layout (in floats)
#define OFF_W        0                    // B*N = 4096 (atomic-passed)
#define OFF_BAR      4096                 // 1 uint counter

// Order-preserving bijection float -> uint32 (ascending)
__device__ __forceinline__ unsigned sortable_f32(float f) {
    unsigned u = __float_as_uint(f);
    return (u & 0x80000000u) ? ~u : (u | 0x80000000u);
}
__device__ __forceinline__ float unsortable_f32(unsigned s) {
    unsigned u = (s & 0x80000000u) ? (s ^ 0x80000000u) : ~s;
    return __uint_as_float(u);
}

// Full ascending bitonic sort of 64 u64 keys across the 64 lanes of a wave.
__device__ __forceinline__ unsigned long long wave_sort64_asc(unsigned long long key, int lane) {
#pragma unroll
    for (int k = 2; k <= 64; k <<= 1) {
#pragma unroll
        for (int j = k >> 1; j > 0; j >>= 1) {
            unsigned long long other = __shfl_xor(key, j);
            bool lower = (lane & j) == 0;
            bool asc = (lane & k) == 0;
            bool takemin = (lower == asc);
            unsigned long long mn = key < other ? key : other;
            unsigned long long mx = key < other ? other : key;
            key = takemin ? mn : mx;
        }
    }
    return key;
}

// Two ascending sorted 64-runs -> smallest 64 of the union, ascending.
__device__ __forceinline__ unsigned long long merge_keep_min64(unsigned long long a, unsigned long long b, int lane) {
    unsigned long long br = __shfl(b, 63 - lane);
    unsigned long long m = a < br ? a : br;
#pragma unroll
    for (int j = 32; j > 0; j >>= 1) {
        unsigned long long other = __shfl_xor(m, j);
        bool lower = (lane & j) == 0;
        unsigned long long mn = m < other ? m : other;
        unsigned long long mx = m < other ? other : m;
        m = lower ? mn : mx;
    }
    return m;
}

// ==================== single-launch kernel: one block per bk ====================
__global__ __launch_bounds__(576) void mega2_kernel(
        const float* __restrict__ src, const float* __restrict__ tgt,
        const float* __restrict__ R, const float* __restrict__ t,
        const float* __restrict__ W1, const float* __restrict__ b1,
        const float* __restrict__ W2, const float* __restrict__ b2,
        const float* __restrict__ Wwl, const float* __restrict__ bwl,
        const float* __restrict__ W3, const float* __restrict__ b3,
        const float* __restrict__ W4, const float* __restrict__ b4,
        float* __restrict__ ws, float* __restrict__ out) {
    __shared__ union {
        struct { float fpts[32][CC_]; float h[32][HH_]; float f[32][DD_]; } fe;   // ~13 KB
        unsigned long long runs[8 * 64];                                          // 4 KB (topk)
        float4 pk[NN_];                                                           // 32 KB (cand)
        struct {
            unsigned long long runs2[8 * 64];   // 4 KB (src select)
            float spts[NS_][CC_];               // 768 B
            float hs[NS_][HH_];                 // 8 KB (fe-h, then dfe layer1)
            float sfeat[NS_][DD_];              // 4 KB
            float outs[NS_][DD_];               // 4 KB
        } sg;
        struct { float th[108][HH_]; float tfeat[NC_][DD_]; } tf;                 // 54 KB
    } u;
    __shared__ float bcast[8];       // c3[0..2], xform[3..5]
    __shared__ int   nnt216[NC_];
    __shared__ float tall[NC_][CC_]; // 6 channels of each candidate's NN point
    __shared__ int   sidx[NS_];
    __shared__ float sdfe[DD_];
    __shared__ float sims[NC_];

    int blk = blockIdx.x;
    int tid = threadIdx.x;                       // 0..575
    int w = tid >> 6, lane = tid & 63;
    int bk = blk;                                // 0..127
    int bat = bk / KK_;
    int kth = bk % KK_;
    float* wbuf = ws + OFF_W;
    unsigned* ctr = (unsigned*)(ws + OFF_BAR);

    // ---------- Stage F: fe (w only) for 32 src points, pass via atomics ----------
    {
        int p0 = blk * 32;                       // 128*32 = 4096 = B*N src points
        for (int idx = tid; idx < 32 * CC_; idx += 576) {
            int pt = idx / CC_, c = idx % CC_;
            int g = p0 + pt; int bb = g / NN_, n = g % NN_;
            u.fe.fpts[pt][c] = src[(bb * CC_ + c) * NN_ + n];
        }
        __syncthreads();
        for (int idx = tid; idx < 32 * HH_; idx += 576) {
            int pt = idx >> 6, tt = idx & 63;
            float s = b1[tt];
#pragma unroll
            for (int c = 0; c < CC_; ++c) s += u.fe.fpts[pt][c] * W1[c * HH_ + tt];
            u.fe.h[pt][tt] = fmaxf(s, 0.f);
        }
        __syncthreads();
        for (int idx = tid; idx < 32 * DD_; idx += 576) {
            int pt = idx >> 5, d = idx & 31;
            float s = b2[d];
#pragma unroll 8
            for (int tt = 0; tt < HH_; ++tt) s += u.fe.h[pt][tt] * W2[tt * DD_ + d];
            u.fe.f[pt][d] = fmaxf(s, 0.f);
        }
        __syncthreads();
        if (tid < 32) {
            float wsum = 0.f;
#pragma unroll 8
            for (int d = 0; d < DD_; ++d) wsum += u.fe.f[tid][d] * Wwl[d];
            wsum += bwl[0];
            __hip_atomic_store(&wbuf[p0 + tid], wsum, __ATOMIC_RELAXED, __HIP_MEMORY_SCOPE_AGENT);
        }
        __syncthreads();                         // drains this block's stores (vmcnt0 before barrier)
        if (tid == 0)
            __hip_atomic_fetch_add(ctr, 1u, __ATOMIC_RELEASE, __HIP_MEMORY_SCOPE_AGENT);
        // spin until all 128 fe chunks published (data passed only via atomics -> no fences)
        if (tid == 0) {
            while (__hip_atomic_load(ctr, __ATOMIC_RELAXED, __HIP_MEMORY_SCOPE_AGENT) < (unsigned)NBLK_)
                __builtin_amdgcn_s_sleep(4);
        }
        __syncthreads();
    }

    // ---------- Stage T: per-block top-K select, pick own keypoint ----------
    {
        if (w < 8) {
            unsigned long long k4[4];
#pragma unroll
            for (int q = 0; q < 4; ++q) {
                int j = w * 256 + q * 64 + lane;
                float wv = __hip_atomic_load(&wbuf[bat * NN_ + j], __ATOMIC_RELAXED, __HIP_MEMORY_SCOPE_AGENT);
                k4[q] = ((unsigned long long)(~sortable_f32(wv)) << 32) | (unsigned)j;
            }
            unsigned long long m1 = merge_keep_min64(wave_sort64_asc(k4[0], lane),
                                                     wave_sort64_asc(k4[1], lane), lane);
            unsigned long long m2 = merge_keep_min64(wave_sort64_asc(k4[2], lane),
                                                     wave_sort64_asc(k4[3], lane), lane);
            u.runs[w * 64 + lane] = merge_keep_min64(m1, m2, lane);
        }
        __syncthreads();
#pragma unroll
        for (int lvl = 4; lvl >= 1; lvl >>= 1) {
            unsigned long long r = 0;
            if (w < lvl) r = merge_keep_min64(u.runs[w * 64 + lane], u.runs[(w + lvl) * 64 + lane], lane);
            __syncthreads();
            if (w < lvl) u.runs[w * 64 + lane] = r;
            __syncthreads();
        }
        if (tid == 0) {
            int bi = (int)(u.runs[kth] & 0xFFFFFFFFu);
            float c3[3];
#pragma unroll
            for (int c = 0; c < CC_; ++c) {
                float v = src[(bat * CC_ + c) * NN_ + bi];
                out[bk * CC_ + c] = v;
                if (c < 3) c3[c] = v;
            }
            bcast[0] = c3[0]; bcast[1] = c3[1]; bcast[2] = c3[2];
#pragma unroll
            for (int i = 0; i < 3; ++i) {
#pragma clang fp contract(off)
                bcast[3 + i] = ((R[i * 3 + 0] * c3[0] + R[i * 3 + 1] * c3[1]) + R[i * 3 + 2] * c3[2]) + t[i];
            }
        }
        __syncthreads();
    }

    // ---------- Stage C: candidate NN over tgt (all 36 xy-groups, 2 passes) ----------
    {
        for (int j = tid; j < NN_; j += 576) {
            float px = tgt[(bat * CC_ + 0) * NN_ + j];
            float py = tgt[(bat * CC_ + 1) * NN_ + j];
            float pz = tgt[(bat * CC_ + 2) * NN_ + j];
            float pw;
            {
#pragma clang fp contract(off)
                pw = (px * px + py * py) + pz * pz;
            }
            u.pk[j ^ ((j >> 6) & 7)] = make_float4(px, py, pz, pw);   // XOR-swizzled slots
        }
        __syncthreads();
        float x0 = bcast[3], x1 = bcast[4], x2 = bcast[5];
        int lg = tid >> 5;                       // 0..17
        int chunk = tid & 31;
        int base = chunk * 64;
        int sw = chunk & 7;
        for (int pass = 0; pass < 2; ++pass) {
            int grp = pass * 18 + lg;            // 0..35 = ix*6+iy
            int ix = grp / 6, iy = grp % 6;
            float cx = x0 + (ix * 0.4f - 1.0f);
            float cy = x1 + (iy * 0.4f - 1.0f);
            float cxy2;
            {
#pragma clang fp contract(off)
                cxy2 = cx * cx + cy * cy;
            }
            float m2x = -2.0f * cx, m2y = -2.0f * cy;
            float aaz[6], m2z[6];
#pragma unroll
            for (int z = 0; z < 6; ++z) {
                float cz = x2 + (z * 0.4f - 1.0f);
                {
#pragma clang fp contract(off)
                    aaz[z] = cxy2 + cz * cz;
                }
                m2z[z] = -2.0f * cz;
            }
            float bv[6];
            int bi[6];
#pragma unroll
            for (int z = 0; z < 6; ++z) { bv[z] = INFINITY; bi[z] = 0; }
            for (int i = 0; i < 64; ++i) {
                int j = base + i;                // ascending j -> first-index ties
                float4 p = u.pk[base + (i ^ sw)];
                float txy;
                {
#pragma clang fp contract(off)
                    txy = m2x * p.x + m2y * p.y;
                }
#pragma unroll
                for (int z = 0; z < 6; ++z) {
                    float d2;
                    {
#pragma clang fp contract(off)
                        d2 = (aaz[z] + p.w) + (txy + m2z[z] * p.z);
                    }
                    if (d2 < bv[z]) { bv[z] = d2; bi[z] = j; }
                }
            }
#pragma unroll
            for (int z = 0; z < 6; ++z) {
                unsigned long long key = ((unsigned long long)sortable_f32(bv[z]) << 32) | (unsigned)bi[z];
#pragma unroll
                for (int m = 1; m <= 16; m <<= 1) {
                    unsigned long long other = __shfl_xor(key, m);
                    key = other < key ? other : key;
                }
                if (chunk == 0) nnt216[grp * 6 + z] = (int)(key & 0xFFFFFFFFu);
            }
        }
        __syncthreads();
    }

    // ---------- Stage S: src grouping + on-demand feats + dfe + max ----------
    {
        float c0 = bcast[0], c1 = bcast[1], c2 = bcast[2];
        float aa;
        {
#pragma clang fp contract(off)
            aa = (c0 * c0 + c1 * c1) + c2 * c2;
        }
        float m2x = -2.0f * c0, m2y = -2.0f * c1, m2z = -2.0f * c2;
        if (w < 8) {
            unsigned long long k4[4];
#pragma unroll
            for (int q = 0; q < 4; ++q) {
                int j = w * 256 + q * 64 + lane;
                float px = src[(bat * CC_ + 0) * NN_ + j];
                float py = src[(bat * CC_ + 1) * NN_ + j];
                float pz = src[(bat * CC_ + 2) * NN_ + j];
                float d2;
                {
#pragma clang fp contract(off)
                    float pw = (px * px + py * py) + pz * pz;
                    d2 = (aa + pw) + ((m2x * px + m2y * py) + m2z * pz);
                }
                k4[q] = ((unsigned long long)sortable_f32(d2) << 32) | (unsigned)j;
            }
            unsigned long long m1 = merge_keep_min64(wave_sort64_asc(k4[0], lane),
                                                     wave_sort64_asc(k4[1], lane), lane);
            unsigned long long m2 = merge_keep_min64(wave_sort64_asc(k4[2], lane),
                                                     wave_sort64_asc(k4[3], lane), lane);
            u.sg.runs2[w * 64 + lane] = merge_keep_min64(m1, m2, lane);
        }
        __syncthreads();
#pragma unroll
        for (int lvl = 4; lvl >= 1; lvl >>= 1) {
            unsigned long long r = 0;
            if (w < lvl) r = merge_keep_min64(u.sg.runs2[w * 64 + lane], u.sg.runs2[(w + lvl) * 64 + lane], lane);
            __syncthreads();
            if (w < lvl) u.sg.runs2[w * 64 + lane] = r;
            __syncthreads();
        }
        if (tid < NS_) {
            unsigned long long key = u.sg.runs2[tid];
            unsigned long long key0 = u.sg.runs2[0];
            float dd = unsortable_f32((unsigned)(key >> 32));
            sidx[tid] = (dd <= 1.0f) ? (int)(key & 0xFFFFFFFFu) : (int)(key0 & 0xFFFFFFFFu);  // R^2=1
        }
        __syncthreads();
        for (int idx = tid; idx < NS_ * CC_; idx += 576) {
            int pt = idx / CC_, c = idx % CC_;
            u.sg.spts[pt][c] = src[(bat * CC_ + c) * NN_ + sidx[pt]];
        }
        __syncthreads();
        // on-demand src feats: h layer
        for (int idx = tid; idx < NS_ * HH_; idx += 576) {
            int pt = idx >> 6, tt = idx & 63;
            float s = b1[tt];
#pragma unroll
            for (int c = 0; c < CC_; ++c) s += u.sg.spts[pt][c] * W1[c * HH_ + tt];
            u.sg.hs[pt][tt] = fmaxf(s, 0.f);
        }
        __syncthreads();
        for (int idx = tid; idx < NS_ * DD_; idx += 576) {
            int pt = idx >> 5, d = idx & 31;
            float s = b2[d];
#pragma unroll 8
            for (int tt = 0; tt < HH_; ++tt) s += u.sg.hs[pt][tt] * W2[tt * DD_ + d];
            u.sg.sfeat[pt][d] = fmaxf(s, 0.f);
        }
        __syncthreads();
        // dfe layer 1 (overwrites hs; sfeat holds inputs)
        if (w < 8) {
#pragma unroll
            for (int ss = 0; ss < 4; ++ss) {
                int s = w * 4 + ss;
                float r0 = u.sg.spts[s][0] - c0, r1 = u.sg.spts[s][1] - c1, r2 = u.sg.spts[s][2] - c2;
                float acc = b3[lane] + r0 * W3[0 * HH_ + lane] + r1 * W3[1 * HH_ + lane] + r2 * W3[2 * HH_ + lane];
#pragma unroll 8
                for (int d = 0; d < DD_; ++d) acc += u.sg.sfeat[s][d] * W3[(3 + d) * HH_ + lane];
                u.sg.hs[s][lane] = fmaxf(acc, 0.f);
            }
        }
        __syncthreads();
        for (int idx = tid; idx < NS_ * DD_; idx += 576) {
            int s = idx >> 5, d = idx & 31;
            float o = b4[d];
#pragma unroll 8
            for (int tt = 0; tt < HH_; ++tt) o += u.sg.hs[s][tt] * W4[tt * DD_ + d];
            u.sg.outs[s][d] = fmaxf(o, 0.f);
        }
        __syncthreads();
        if (tid < DD_) {
            float m = -INFINITY;
#pragma unroll 8
            for (int s = 0; s < NS_; ++s) m = fmaxf(m, u.sg.outs[s][tid]);
            sdfe[tid] = m;
        }
        __syncthreads();
    }

    // ---------- Stage G: on-demand tgt feats for the 216 chosen NN ----------
    {
        for (int idx = tid; idx < NC_ * CC_; idx += 576) {
            int pt = idx / CC_, c = idx % CC_;
            tall[pt][c] = tgt[(bat * CC_ + c) * NN_ + nnt216[pt]];
        }
        __syncthreads();
        for (int ch = 0; ch < 2; ++ch) {
            for (int idx = tid; idx < 108 * HH_; idx += 576) {
                int pl = idx >> 6, tt = idx & 63;
                int pt = ch * 108 + pl;
                float s = b1[tt];
#pragma unroll
                for (int c = 0; c < CC_; ++c) s += tall[pt][c] * W1[c * HH_ + tt];
                u.tf.th[pl][tt] = fmaxf(s, 0.f);
            }
            __syncthreads();
            for (int idx = tid; idx < 108 * DD_; idx += 576) {
                int pl = idx >> 5, d = idx & 31;
                int pt = ch * 108 + pl;
                float s = b2[d];
#pragma unroll 8
                for (int tt = 0; tt < HH_; ++tt) s += u.tf.th[pl][tt] * W2[tt * DD_ + d];
                u.tf.tfeat[pt][d] = fmaxf(s, 0.f);
            }
            __syncthreads();
        }
    }

    // ---------- Stage P: per-candidate MLP + sim + softmax + vcp ----------
    {
        float x0 = bcast[3], x1 = bcast[4], x2 = bcast[5];
        if (tid < NC_) {
            int c = tid;
            int ix = c / 36, iy = (c / 6) % 6, iz = c % 6;
            float cx = x0 + (ix * 0.4f - 1.0f);
            float cy = x1 + (iy * 0.4f - 1.0f);
            float cz = x2 + (iz * 0.4f - 1.0f);
            float x[3 + DD_];
            x[0] = tall[c][0] - cx; x[1] = tall[c][1] - cy; x[2] = tall[c][2] - cz;
#pragma unroll
            for (int d = 0; d < DD_; ++d) x[3 + d] = u.tf.tfeat[c][d];
            float o[DD_];
#pragma unroll
            for (int d = 0; d < DD_; ++d) o[d] = b4[d];
            for (int tt = 0; tt < HH_; ++tt) {
                float acc = b3[tt];
#pragma unroll
                for (int cc = 0; cc < 3 + DD_; ++cc) acc += x[cc] * W3[cc * HH_ + tt];
                float ht = fmaxf(acc, 0.f);
#pragma unroll
                for (int d = 0; d < DD_; ++d) o[d] += ht * W4[tt * DD_ + d];
            }
            float sim = 0.f;
#pragma unroll
            for (int d = 0; d < DD_; ++d) sim += fmaxf(o[d], 0.f) * sdfe[d];
            sims[c] = sim;
        }
        __syncthreads();
        if (tid < 64) {
            float m = -INFINITY;
            for (int c = lane; c < NC_; c += 64) m = fmaxf(m, sims[c]);
#pragma unroll
            for (int sh = 32; sh; sh >>= 1) m = fmaxf(m, __shfl_xor(m, sh));
            float se = 0.f, v0 = 0.f, v1 = 0.f, v2 = 0.f;
            for (int c = lane; c < NC_; c += 64) {
                float e = expf(sims[c] - m);
                int ix = c / 36, iy = (c / 6) % 6, iz = c % 6;
                se += e;
                v0 += e * (x0 + (ix * 0.4f - 1.0f));
                v1 += e * (x1 + (iy * 0.4f - 1.0f));
                v2 += e * (x2 + (iz * 0.4f - 1.0f));
            }
#pragma unroll
            for (int sh = 32; sh; sh >>= 1) {
                se += __shfl_xor(se, sh);
                v0 += __shfl_xor(v0, sh);
                v1 += __shfl_xor(v1, sh);
                v2 += __shfl_xor(v2, sh);
            }
            if (lane == 0) {
                float inv = 1.0f / se;
                float* oo = out + BB_ * KK_ * CC_ + bk * 3;
                oo[0] = v0 * inv;
                oo[1] = v1 * inv;
                oo[2] = v2 * inv;
            }
        }
    }
}

extern "C" void kernel_launch(void* const* d_in, const int* in_sizes, int n_in,
                              void* d_out, int out_size, void* d_ws, size_t ws_size,
                              hipStream_t stream) {
    const float* src = (const float*)d_in[0];
    const float* tgt = (const float*)d_in[1];
    const float* R   = (const float*)d_in[2];
    const float* t   = (const float*)d_in[3];
    const float* W1  = (const float*)d_in[4];
    const float* b1  = (const float*)d_in[5];
    const float* W2  = (const float*)d_in[6];
    const float* b2  = (const float*)d_in[7];
    const float* Wwl = (const float*)d_in[8];
    const float* bwl = (const float*)d_in[9];
    const float* W3  = (const float*)d_in[10];
    const float* b3  = (const float*)d_in[11];
    const float* W4  = (const float*)d_in[12];
    const float* b4  = (const float*)d_in[13];
    float* ws  = (float*)d_ws;
    float* out = (float*)d_out;

    // zero the fe-done counter (captured graph node, runs every replay)
    hipMemsetAsync(ws + OFF_BAR, 0, sizeof(unsigned), stream);

    void* args[] = {(void*)&src, (void*)&tgt, (void*)&R, (void*)&t,
                    (void*)&W1, (void*)&b1, (void*)&W2, (void*)&b2,
                    (void*)&Wwl, (void*)&bwl, (void*)&W3, (void*)&b3,
                    (void*)&W4, (void*)&b4, (void*)&ws, (void*)&out};
    hipError_t e = hipLaunchCooperativeKernel((const void*)mega2_kernel,
                                              dim3(NBLK_), dim3(576),
                                              args, 0, stream);
    if (e != hipSuccess) {
        // plain launch: 128 blocks x 576 thr (<= 256 CUs) are co-resident anyway,
        // so the fe counter-barrier cannot deadlock.
        mega2_kernel<<<NBLK_, 576, 0, stream>>>(src, tgt, R, t, W1, b1, W2, b2,
                                                Wwl, bwl, W3, b3, W4, b4, ws, out);
    }
}

// Round 10
// 114.086 us; speedup vs baseline: 1.4437x; 1.2093x over previous
//
#include <hip/hip_runtime.h>
#include <math.h>

// Problem constants
#define BB_ 2      // batch
#define CC_ 6      // channels
#define NN_ 2048   // points
#define KK_ 64     // keypoints
#define NS_ 32     // neighbors
#define DD_ 32     // feat dim
#define NC_ 216    // candidate grid (6^3)
#define HH_ 64     // hidden dim

// ws layout (element units)
#define OFF_W      0        // 4096 floats
#define OFF_FLAG   4096     // 128 uints (uint* view)
#define OFF_NNT    4224     // 27648 ints (int* view)

// Order-preserving bijection float -> uint32 (ascending)
__device__ __forceinline__ unsigned sortable_f32(float f) {
    unsigned u = __float_as_uint(f);
    return (u & 0x80000000u) ? ~u : (u | 0x80000000u);
}
__device__ __forceinline__ float unsortable_f32(unsigned s) {
    unsigned u = (s & 0x80000000u) ? (s ^ 0x80000000u) : ~s;
    return __uint_as_float(u);
}

__device__ __forceinline__ unsigned long long wave_sort64_asc(unsigned long long key, int lane) {
#pragma unroll
    for (int k = 2; k <= 64; k <<= 1) {
#pragma unroll
        for (int j = k >> 1; j > 0; j >>= 1) {
            unsigned long long other = __shfl_xor(key, j);
            bool lower = (lane & j) == 0;
            bool asc = (lane & k) == 0;
            bool takemin = (lower == asc);
            unsigned long long mn = key < other ? key : other;
            unsigned long long mx = key < other ? other : key;
            key = takemin ? mn : mx;
        }
    }
    return key;
}

__device__ __forceinline__ unsigned long long merge_keep_min64(unsigned long long a, unsigned long long b, int lane) {
    unsigned long long br = __shfl(b, 63 - lane);
    unsigned long long m = a < br ? a : br;
#pragma unroll
    for (int j = 32; j > 0; j >>= 1) {
        unsigned long long other = __shfl_xor(m, j);
        bool lower = (lane & j) == 0;
        unsigned long long mn = m < other ? m : other;
        unsigned long long mx = m < other ? other : m;
        m = lower ? mn : mx;
    }
    return m;
}

// -------------------- K1: keypoint weights only --------------------
__global__ void fe_w_kernel(const float* __restrict__ src,
                            const float* __restrict__ W1, const float* __restrict__ b1,
                            const float* __restrict__ W2, const float* __restrict__ b2,
                            const float* __restrict__ Wwl, const float* __restrict__ bwl,
                            float* __restrict__ ws) {
    int g = blockIdx.x * blockDim.x + threadIdx.x;     // 0..4095
    int b = g / NN_, n = g % NN_;
    float x[CC_];
#pragma unroll
    for (int c = 0; c < CC_; ++c) x[c] = src[(b * CC_ + c) * NN_ + n];
    float h[HH_];
#pragma unroll
    for (int t = 0; t < HH_; ++t) {
        float s = b1[t];
#pragma unroll
        for (int c = 0; c < CC_; ++c) s += x[c] * W1[c * HH_ + t];
        h[t] = fmaxf(s, 0.f);
    }
    float wsum = 0.f;
#pragma unroll 4
    for (int d = 0; d < DD_; ++d) {
        float s = b2[d];
#pragma unroll
        for (int t = 0; t < HH_; ++t) s += h[t] * W2[t * DD_ + d];
        s = fmaxf(s, 0.f);
        wsum += s * Wwl[d];
    }
    (ws + OFF_W)[g] = wsum + bwl[0];
}

// -------------------- K2: everything else, 384 blocks x 576 ----------
// blocks 0..255  : cand role (bk=blk>>1, half=blk&1) -> NNT via atomics + flag
// blocks 256..383: src role (bk=blk-256) -> keypts out, dfe, wait flags, sim+vcp
__global__ __launch_bounds__(576) void mid2_kernel(
        const float* __restrict__ src, const float* __restrict__ tgt,
        const float* __restrict__ R, const float* __restrict__ t,
        const float* __restrict__ W1, const float* __restrict__ b1,
        const float* __restrict__ W2, const float* __restrict__ b2,
        const float* __restrict__ W3, const float* __restrict__ b3,
        const float* __restrict__ W4, const float* __restrict__ b4,
        float* __restrict__ ws, float* __restrict__ out) {
    __shared__ union {
        unsigned long long runs[8 * 64];                 // 4 KB (topk / src select)
        float4 pk[NN_];                                  // 32 KB (cand)
        struct {
            unsigned long long runs2[8 * 64];            // 4 KB
            float spts[NS_][CC_];
            float hs[NS_][HH_];
            float sfeat[NS_][DD_];
            float outs[NS_][DD_];
        } sg;
        struct { float th[108][HH_]; float tfeat[NC_][DD_]; } tf;  // 54 KB
    } u;
    __shared__ float bcast[8];
    __shared__ int   nnt216[NC_];
    __shared__ float tall[NC_][CC_];
    __shared__ int   sidx[NS_];
    __shared__ float sdfe[DD_];
    __shared__ float sims[NC_];

    int blk = blockIdx.x;
    int tid = threadIdx.x;
    int w = tid >> 6, lane = tid & 63;
    bool cand_role = (blk < 2 * BB_ * KK_);
    int bk = cand_role ? (blk >> 1) : (blk - 2 * BB_ * KK_);
    int bat = bk / KK_, kth = bk % KK_;
    const float* wbuf = ws + OFF_W;
    unsigned* flags = (unsigned*)ws + OFF_FLAG;
    int* nntb = (int*)ws + OFF_NNT;

    // ---------- per-block top-K select (normal loads; fe_w synced by kernel boundary) ----------
    {
        if (w < 8) {
            unsigned long long k4[4];
#pragma unroll
            for (int q = 0; q < 4; ++q) {
                int j = w * 256 + q * 64 + lane;
                k4[q] = ((unsigned long long)(~sortable_f32(wbuf[bat * NN_ + j])) << 32) | (unsigned)j;
            }
            unsigned long long m1 = merge_keep_min64(wave_sort64_asc(k4[0], lane),
                                                     wave_sort64_asc(k4[1], lane), lane);
            unsigned long long m2 = merge_keep_min64(wave_sort64_asc(k4[2], lane),
                                                     wave_sort64_asc(k4[3], lane), lane);
            u.runs[w * 64 + lane] = merge_keep_min64(m1, m2, lane);
        }
        __syncthreads();
#pragma unroll
        for (int lvl = 4; lvl >= 1; lvl >>= 1) {
            unsigned long long r = 0;
            if (w < lvl) r = merge_keep_min64(u.runs[w * 64 + lane], u.runs[(w + lvl) * 64 + lane], lane);
            __syncthreads();
            if (w < lvl) u.runs[w * 64 + lane] = r;
            __syncthreads();
        }
        if (tid == 0) {
            int bi = (int)(u.runs[kth] & 0xFFFFFFFFu);
            float c3[3];
#pragma unroll
            for (int c = 0; c < CC_; ++c) {
                float v = src[(bat * CC_ + c) * NN_ + bi];
                if (!cand_role) out[bk * CC_ + c] = v;   // exactly one writer per bk
                if (c < 3) c3[c] = v;
            }
            bcast[0] = c3[0]; bcast[1] = c3[1]; bcast[2] = c3[2];
#pragma unroll
            for (int i = 0; i < 3; ++i) {
#pragma clang fp contract(off)
                bcast[3 + i] = ((R[i * 3 + 0] * c3[0] + R[i * 3 + 1] * c3[1]) + R[i * 3 + 2] * c3[2]) + t[i];
            }
        }
        __syncthreads();
    }

    if (cand_role) {
        // ---------- cand role: NN for 18 xy-groups ----------
        int half = blk & 1;
        for (int j = tid; j < NN_; j += 576) {
            float px = tgt[(bat * CC_ + 0) * NN_ + j];
            float py = tgt[(bat * CC_ + 1) * NN_ + j];
            float pz = tgt[(bat * CC_ + 2) * NN_ + j];
            float pw;
            {
#pragma clang fp contract(off)
                pw = (px * px + py * py) + pz * pz;
            }
            u.pk[j ^ ((j >> 6) & 7)] = make_float4(px, py, pz, pw);
        }
        __syncthreads();
        float x0 = bcast[3], x1 = bcast[4], x2 = bcast[5];
        int lg = tid >> 5;
        int chunk = tid & 31;
        int grp = half * 18 + lg;
        int ix = grp / 6, iy = grp % 6;
        float cx = x0 + (ix * 0.4f - 1.0f);
        float cy = x1 + (iy * 0.4f - 1.0f);
        float cxy2;
        {
#pragma clang fp contract(off)
            cxy2 = cx * cx + cy * cy;
        }
        float m2x = -2.0f * cx, m2y = -2.0f * cy;
        float aaz[6], m2z[6];
#pragma unroll
        for (int z = 0; z < 6; ++z) {
            float cz = x2 + (z * 0.4f - 1.0f);
            {
#pragma clang fp contract(off)
                aaz[z] = cxy2 + cz * cz;
            }
            m2z[z] = -2.0f * cz;
        }
        float bv[6];
        int bi[6];
#pragma unroll
        for (int z = 0; z < 6; ++z) { bv[z] = INFINITY; bi[z] = 0; }
        int base = chunk * 64;
        int sw = chunk & 7;
        for (int i = 0; i < 64; ++i) {
            int j = base + i;                            // ascending j -> first-index ties
            float4 p = u.pk[base + (i ^ sw)];            // slot(j) for j=base+i
            float txy;
            {
#pragma clang fp contract(off)
                txy = m2x * p.x + m2y * p.y;
            }
#pragma unroll
            for (int z = 0; z < 6; ++z) {
                float d2;
                {
#pragma clang fp contract(off)
                    d2 = (aaz[z] + p.w) + (txy + m2z[z] * p.z);
                }
                if (d2 < bv[z]) { bv[z] = d2; bi[z] = j; }
            }
        }
#pragma unroll
        for (int z = 0; z < 6; ++z) {
            unsigned long long key = ((unsigned long long)sortable_f32(bv[z]) << 32) | (unsigned)bi[z];
#pragma unroll
            for (int m = 1; m <= 16; m <<= 1) {
                unsigned long long other = __shfl_xor(key, m);
                key = other < key ? other : key;
            }
            if (chunk == 0)
                __hip_atomic_store(&nntb[bk * NC_ + grp * 6 + z], (int)(key & 0xFFFFFFFFu),
                                   __ATOMIC_RELAXED, __HIP_MEMORY_SCOPE_AGENT);
        }
        __syncthreads();   // vmcnt(0): all NNT stores complete before flag release
        if (tid == 0)
            __hip_atomic_fetch_add(&flags[bk], 1u, __ATOMIC_RELEASE, __HIP_MEMORY_SCOPE_AGENT);
    } else {
        // ---------- src role ----------
        float c0 = bcast[0], c1 = bcast[1], c2 = bcast[2];
        float aa;
        {
#pragma clang fp contract(off)
            aa = (c0 * c0 + c1 * c1) + c2 * c2;
        }
        float m2x = -2.0f * c0, m2y = -2.0f * c1, m2z = -2.0f * c2;
        if (w < 8) {
            unsigned long long k4[4];
#pragma unroll
            for (int q = 0; q < 4; ++q) {
                int j = w * 256 + q * 64 + lane;
                float px = src[(bat * CC_ + 0) * NN_ + j];
                float py = src[(bat * CC_ + 1) * NN_ + j];
                float pz = src[(bat * CC_ + 2) * NN_ + j];
                float d2;
                {
#pragma clang fp contract(off)
                    float pw = (px * px + py * py) + pz * pz;
                    d2 = (aa + pw) + ((m2x * px + m2y * py) + m2z * pz);
                }
                k4[q] = ((unsigned long long)sortable_f32(d2) << 32) | (unsigned)j;
            }
            unsigned long long m1 = merge_keep_min64(wave_sort64_asc(k4[0], lane),
                                                     wave_sort64_asc(k4[1], lane), lane);
            unsigned long long m2 = merge_keep_min64(wave_sort64_asc(k4[2], lane),
                                                     wave_sort64_asc(k4[3], lane), lane);
            u.sg.runs2[w * 64 + lane] = merge_keep_min64(m1, m2, lane);
        }
        __syncthreads();
#pragma unroll
        for (int lvl = 4; lvl >= 1; lvl >>= 1) {
            unsigned long long r = 0;
            if (w < lvl) r = merge_keep_min64(u.sg.runs2[w * 64 + lane], u.sg.runs2[(w + lvl) * 64 + lane], lane);
            __syncthreads();
            if (w < lvl) u.sg.runs2[w * 64 + lane] = r;
            __syncthreads();
        }
        if (tid < NS_) {
            unsigned long long key = u.sg.runs2[tid];
            unsigned long long key0 = u.sg.runs2[0];
            float dd = unsortable_f32((unsigned)(key >> 32));
            sidx[tid] = (dd <= 1.0f) ? (int)(key & 0xFFFFFFFFu) : (int)(key0 & 0xFFFFFFFFu);  // R^2=1
        }
        __syncthreads();
        for (int idx = tid; idx < NS_ * CC_; idx += 576) {
            int pt = idx / CC_, c = idx % CC_;
            u.sg.spts[pt][c] = src[(bat * CC_ + c) * NN_ + sidx[pt]];
        }
        __syncthreads();
        for (int idx = tid; idx < NS_ * HH_; idx += 576) {
            int pt = idx >> 6, tt = idx & 63;
            float s = b1[tt];
#pragma unroll
            for (int c = 0; c < CC_; ++c) s += u.sg.spts[pt][c] * W1[c * HH_ + tt];
            u.sg.hs[pt][tt] = fmaxf(s, 0.f);
        }
        __syncthreads();
        for (int idx = tid; idx < NS_ * DD_; idx += 576) {
            int pt = idx >> 5, d = idx & 31;
            float s = b2[d];
#pragma unroll 8
            for (int tt = 0; tt < HH_; ++tt) s += u.sg.hs[pt][tt] * W2[tt * DD_ + d];
            u.sg.sfeat[pt][d] = fmaxf(s, 0.f);
        }
        __syncthreads();
        if (w < 8) {
#pragma unroll
            for (int ss = 0; ss < 4; ++ss) {
                int s = w * 4 + ss;
                float r0 = u.sg.spts[s][0] - c0, r1 = u.sg.spts[s][1] - c1, r2 = u.sg.spts[s][2] - c2;
                float acc = b3[lane] + r0 * W3[0 * HH_ + lane] + r1 * W3[1 * HH_ + lane] + r2 * W3[2 * HH_ + lane];
#pragma unroll 8
                for (int d = 0; d < DD_; ++d) acc += u.sg.sfeat[s][d] * W3[(3 + d) * HH_ + lane];
                u.sg.hs[s][lane] = fmaxf(acc, 0.f);
            }
        }
        __syncthreads();
        for (int idx = tid; idx < NS_ * DD_; idx += 576) {
            int s = idx >> 5, d = idx & 31;
            float o = b4[d];
#pragma unroll 8
            for (int tt = 0; tt < HH_; ++tt) o += u.sg.hs[s][tt] * W4[tt * DD_ + d];
            u.sg.outs[s][d] = fmaxf(o, 0.f);
        }
        __syncthreads();
        if (tid < DD_) {
            float m = -INFINITY;
#pragma unroll 8
            for (int s = 0; s < NS_; ++s) m = fmaxf(m, u.sg.outs[s][tid]);
            sdfe[tid] = m;
        }

        // ---------- wait for both cand halves, pull NNT ----------
        __syncthreads();
        if (tid == 0) {
            while (__hip_atomic_load(&flags[bk], __ATOMIC_ACQUIRE, __HIP_MEMORY_SCOPE_AGENT) < 2u)
                __builtin_amdgcn_s_sleep(2);
        }
        __syncthreads();
        for (int idx = tid; idx < NC_; idx += 576)
            nnt216[idx] = __hip_atomic_load(&nntb[bk * NC_ + idx], __ATOMIC_RELAXED, __HIP_MEMORY_SCOPE_AGENT);
        __syncthreads();

        // ---------- tgt feats for the 216 chosen NN ----------
        for (int idx = tid; idx < NC_ * CC_; idx += 576) {
            int pt = idx / CC_, c = idx % CC_;
            tall[pt][c] = tgt[(bat * CC_ + c) * NN_ + nnt216[pt]];
        }
        __syncthreads();
        for (int ch = 0; ch < 2; ++ch) {
            for (int idx = tid; idx < 108 * HH_; idx += 576) {
                int pl = idx >> 6, tt = idx & 63;
                int pt = ch * 108 + pl;
                float s = b1[tt];
#pragma unroll
                for (int c = 0; c < CC_; ++c) s += tall[pt][c] * W1[c * HH_ + tt];
                u.tf.th[pl][tt] = fmaxf(s, 0.f);
            }
            __syncthreads();
            for (int idx = tid; idx < 108 * DD_; idx += 576) {
                int pl = idx >> 5, d = idx & 31;
                int pt = ch * 108 + pl;
                float s = b2[d];
#pragma unroll 8
                for (int tt = 0; tt < HH_; ++tt) s += u.tf.th[pl][tt] * W2[tt * DD_ + d];
                u.tf.tfeat[pt][d] = fmaxf(s, 0.f);
            }
            __syncthreads();
        }

        // ---------- per-candidate MLP + sim + softmax + vcp ----------
        float x0 = bcast[3], x1 = bcast[4], x2 = bcast[5];
        if (tid < NC_) {
            int c = tid;
            int ix = c / 36, iy = (c / 6) % 6, iz = c % 6;
            float cx = x0 + (ix * 0.4f - 1.0f);
            float cy = x1 + (iy * 0.4f - 1.0f);
            float cz = x2 + (iz * 0.4f - 1.0f);
            float x[3 + DD_];
            x[0] = tall[c][0] - cx; x[1] = tall[c][1] - cy; x[2] = tall[c][2] - cz;
#pragma unroll
            for (int d = 0; d < DD_; ++d) x[3 + d] = u.tf.tfeat[c][d];
            float o[DD_];
#pragma unroll
            for (int d = 0; d < DD_; ++d) o[d] = b4[d];
            for (int tt = 0; tt < HH_; ++tt) {
                float acc = b3[tt];
#pragma unroll
                for (int cc = 0; cc < 3 + DD_; ++cc) acc += x[cc] * W3[cc * HH_ + tt];
                float ht = fmaxf(acc, 0.f);
#pragma unroll
                for (int d = 0; d < DD_; ++d) o[d] += ht * W4[tt * DD_ + d];
            }
            float sim = 0.f;
#pragma unroll
            for (int d = 0; d < DD_; ++d) sim += fmaxf(o[d], 0.f) * sdfe[d];
            sims[c] = sim;
        }
        __syncthreads();
        if (tid < 64) {
            float m = -INFINITY;
            for (int c = lane; c < NC_; c += 64) m = fmaxf(m, sims[c]);
#pragma unroll
            for (int sh = 32; sh; sh >>= 1) m = fmaxf(m, __shfl_xor(m, sh));
            float se = 0.f, v0 = 0.f, v1 = 0.f, v2 = 0.f;
            for (int c = lane; c < NC_; c += 64) {
                float e = expf(sims[c] - m);
                int ix = c / 36, iy = (c / 6) % 6, iz = c % 6;
                se += e;
                v0 += e * (x0 + (ix * 0.4f - 1.0f));
                v1 += e * (x1 + (iy * 0.4f - 1.0f));
                v2 += e * (x2 + (iz * 0.4f - 1.0f));
            }
#pragma unroll
            for (int sh = 32; sh; sh >>= 1) {
                se += __shfl_xor(se, sh);
                v0 += __shfl_xor(v0, sh);
                v1 += __shfl_xor(v1, sh);
                v2 += __shfl_xor(v2, sh);
            }
            if (lane == 0) {
                float inv = 1.0f / se;
                float* oo = out + BB_ * KK_ * CC_ + bk * 3;
                oo[0] = v0 * inv;
                oo[1] = v1 * inv;
                oo[2] = v2 * inv;
            }
        }
    }
}

extern "C" void kernel_launch(void* const* d_in, const int* in_sizes, int n_in,
                              void* d_out, int out_size, void* d_ws, size_t ws_size,
                              hipStream_t stream) {
    const float* src = (const float*)d_in[0];
    const float* tgt = (const float*)d_in[1];
    const float* R   = (const float*)d_in[2];
    const float* t   = (const float*)d_in[3];
    const float* W1  = (const float*)d_in[4];
    const float* b1  = (const float*)d_in[5];
    const float* W2  = (const float*)d_in[6];
    const float* b2  = (const float*)d_in[7];
    const float* Wwl = (const float*)d_in[8];
    const float* bwl = (const float*)d_in[9];
    const float* W3  = (const float*)d_in[10];
    const float* b3  = (const float*)d_in[11];
    const float* W4  = (const float*)d_in[12];
    const float* b4  = (const float*)d_in[13];
    float* ws  = (float*)d_ws;
    float* out = (float*)d_out;

    // zero the 128 per-bk flags (captured graph node, runs every replay)
    hipMemsetAsync((char*)d_ws + OFF_FLAG * 4, 0, 128 * sizeof(unsigned), stream);

    fe_w_kernel<<<16, 256, 0, stream>>>(src, W1, b1, W2, b2, Wwl, bwl, ws);
    mid2_kernel<<<3 * BB_ * KK_, 576, 0, stream>>>(src, tgt, R, t, W1, b1, W2, b2,
                                                   W3, b3, W4, b4, ws, out);
}

// Round 11
// 110.270 us; speedup vs baseline: 1.4937x; 1.0346x over previous
//
#include <hip/hip_runtime.h>
#include <math.h>

// Problem constants
#define BB_ 2      // batch
#define CC_ 6      // channels
#define NN_ 2048   // points
#define KK_ 64     // keypoints
#define NS_ 32     // neighbors
#define DD_ 32     // feat dim
#define NC_ 216    // candidate grid (6^3)
#define HH_ 64     // hidden dim

// ws layout (element units)
#define OFF_W      0        // 4096 floats
#define OFF_NNT    4096     // 27648 ints (int* view)

// Order-preserving bijection float -> uint32 (ascending)
__device__ __forceinline__ unsigned sortable_f32(float f) {
    unsigned u = __float_as_uint(f);
    return (u & 0x80000000u) ? ~u : (u | 0x80000000u);
}
__device__ __forceinline__ float unsortable_f32(unsigned s) {
    unsigned u = (s & 0x80000000u) ? (s ^ 0x80000000u) : ~s;
    return __uint_as_float(u);
}

__device__ __forceinline__ unsigned long long wave_sort64_asc(unsigned long long key, int lane) {
#pragma unroll
    for (int k = 2; k <= 64; k <<= 1) {
#pragma unroll
        for (int j = k >> 1; j > 0; j >>= 1) {
            unsigned long long other = __shfl_xor(key, j);
            bool lower = (lane & j) == 0;
            bool asc = (lane & k) == 0;
            bool takemin = (lower == asc);
            unsigned long long mn = key < other ? key : other;
            unsigned long long mx = key < other ? other : key;
            key = takemin ? mn : mx;
        }
    }
    return key;
}

__device__ __forceinline__ unsigned long long merge_keep_min64(unsigned long long a, unsigned long long b, int lane) {
    unsigned long long br = __shfl(b, 63 - lane);
    unsigned long long m = a < br ? a : br;
#pragma unroll
    for (int j = 32; j > 0; j >>= 1) {
        unsigned long long other = __shfl_xor(m, j);
        bool lower = (lane & j) == 0;
        unsigned long long mn = m < other ? m : other;
        unsigned long long mx = m < other ? other : m;
        m = lower ? mn : mx;
    }
    return m;
}

// 576-thread (9 wave) select: waves 0..7 build sorted 64-runs from 4 keys/lane,
// LDS merge tree leaves runs[0..63] = 64 smallest (ascending). Caller provides keys.
// (inlined at each use site below)

// -------------------- K1: keypoint weights only --------------------
__global__ void fe_w_kernel(const float* __restrict__ src,
                            const float* __restrict__ W1, const float* __restrict__ b1,
                            const float* __restrict__ W2, const float* __restrict__ b2,
                            const float* __restrict__ Wwl, const float* __restrict__ bwl,
                            float* __restrict__ ws) {
    int g = blockIdx.x * blockDim.x + threadIdx.x;     // 0..4095
    int b = g / NN_, n = g % NN_;
    float x[CC_];
#pragma unroll
    for (int c = 0; c < CC_; ++c) x[c] = src[(b * CC_ + c) * NN_ + n];
    float h[HH_];
#pragma unroll
    for (int t = 0; t < HH_; ++t) {
        float s = b1[t];
#pragma unroll
        for (int c = 0; c < CC_; ++c) s += x[c] * W1[c * HH_ + t];
        h[t] = fmaxf(s, 0.f);
    }
    float wsum = 0.f;
#pragma unroll 4
    for (int d = 0; d < DD_; ++d) {
        float s = b2[d];
#pragma unroll
        for (int t = 0; t < HH_; ++t) s += h[t] * W2[t * DD_ + d];
        s = fmaxf(s, 0.f);
        wsum += s * Wwl[d];
    }
    (ws + OFF_W)[g] = wsum + bwl[0];
}

// -------------------- K2: candidate NN (256 blocks x 576) --------------------
// block = (bk, half). topk-select for xform, stage tgt pack, scan 18 xy-groups.
__global__ __launch_bounds__(576) void cand_kernel(
        const float* __restrict__ src, const float* __restrict__ tgt,
        const float* __restrict__ R, const float* __restrict__ t,
        float* __restrict__ ws) {
    __shared__ union {
        unsigned long long runs[8 * 64];
        float4 pk[NN_];
    } u;
    __shared__ float bcast[4];
    int blk = blockIdx.x;
    int tid = threadIdx.x;
    int w = tid >> 6, lane = tid & 63;
    int bk = blk >> 1;
    int half = blk & 1;
    int bat = bk / KK_, kth = bk % KK_;
    const float* wbuf = ws + OFF_W;
    int* nntb = (int*)ws + OFF_NNT;

    // per-block top-K select -> xform of own keypoint
    if (w < 8) {
        unsigned long long k4[4];
#pragma unroll
        for (int q = 0; q < 4; ++q) {
            int j = w * 256 + q * 64 + lane;
            k4[q] = ((unsigned long long)(~sortable_f32(wbuf[bat * NN_ + j])) << 32) | (unsigned)j;
        }
        unsigned long long m1 = merge_keep_min64(wave_sort64_asc(k4[0], lane),
                                                 wave_sort64_asc(k4[1], lane), lane);
        unsigned long long m2 = merge_keep_min64(wave_sort64_asc(k4[2], lane),
                                                 wave_sort64_asc(k4[3], lane), lane);
        u.runs[w * 64 + lane] = merge_keep_min64(m1, m2, lane);
    }
    __syncthreads();
#pragma unroll
    for (int lvl = 4; lvl >= 1; lvl >>= 1) {
        unsigned long long r = 0;
        if (w < lvl) r = merge_keep_min64(u.runs[w * 64 + lane], u.runs[(w + lvl) * 64 + lane], lane);
        __syncthreads();
        if (w < lvl) u.runs[w * 64 + lane] = r;
        __syncthreads();
    }
    if (tid == 0) {
        int bi = (int)(u.runs[kth] & 0xFFFFFFFFu);
        float c3[3];
#pragma unroll
        for (int c = 0; c < 3; ++c) c3[c] = src[(bat * CC_ + c) * NN_ + bi];
#pragma unroll
        for (int i = 0; i < 3; ++i) {
#pragma clang fp contract(off)
            bcast[i] = ((R[i * 3 + 0] * c3[0] + R[i * 3 + 1] * c3[1]) + R[i * 3 + 2] * c3[2]) + t[i];
        }
    }
    __syncthreads();

    // stage tgt pack (XOR-swizzled slots)
    for (int j = tid; j < NN_; j += 576) {
        float px = tgt[(bat * CC_ + 0) * NN_ + j];
        float py = tgt[(bat * CC_ + 1) * NN_ + j];
        float pz = tgt[(bat * CC_ + 2) * NN_ + j];
        float pw;
        {
#pragma clang fp contract(off)
            pw = (px * px + py * py) + pz * pz;
        }
        u.pk[j ^ ((j >> 6) & 7)] = make_float4(px, py, pz, pw);
    }
    float x0 = bcast[0], x1 = bcast[1], x2 = bcast[2];
    __syncthreads();

    int lg = tid >> 5;                           // 0..17
    int chunk = tid & 31;
    int grp = half * 18 + lg;                    // 0..35 = ix*6+iy
    int ix = grp / 6, iy = grp % 6;
    float cx = x0 + (ix * 0.4f - 1.0f);
    float cy = x1 + (iy * 0.4f - 1.0f);
    float cxy2;
    {
#pragma clang fp contract(off)
        cxy2 = cx * cx + cy * cy;
    }
    float m2x = -2.0f * cx, m2y = -2.0f * cy;
    float aaz[6], m2z[6];
#pragma unroll
    for (int z = 0; z < 6; ++z) {
        float cz = x2 + (z * 0.4f - 1.0f);
        {
#pragma clang fp contract(off)
            aaz[z] = cxy2 + cz * cz;
        }
        m2z[z] = -2.0f * cz;
    }
    float bv[6];
    int bi6[6];
#pragma unroll
    for (int z = 0; z < 6; ++z) { bv[z] = INFINITY; bi6[z] = 0; }
    int base = chunk * 64;
    int sw = chunk & 7;
    for (int i = 0; i < 64; ++i) {
        int j = base + i;                        // ascending j -> first-index ties
        float4 p = u.pk[base + (i ^ sw)];        // slot(j) for j=base+i
        float txy;
        {
#pragma clang fp contract(off)
            txy = m2x * p.x + m2y * p.y;
        }
#pragma unroll
        for (int z = 0; z < 6; ++z) {
            float d2;
            {
#pragma clang fp contract(off)
                d2 = (aaz[z] + p.w) + (txy + m2z[z] * p.z);
            }
            if (d2 < bv[z]) { bv[z] = d2; bi6[z] = j; }
        }
    }
#pragma unroll
    for (int z = 0; z < 6; ++z) {
        unsigned long long key = ((unsigned long long)sortable_f32(bv[z]) << 32) | (unsigned)bi6[z];
#pragma unroll
        for (int m = 1; m <= 16; m <<= 1) {
            unsigned long long other = __shfl_xor(key, m);
            key = other < key ? other : key;
        }
        if (chunk == 0) nntb[bk * NC_ + grp * 6 + z] = (int)(key & 0xFFFFFFFFu);
    }
}

// -------------------- K3: src side + finish (128 blocks x 576) --------------------
__global__ __launch_bounds__(576) void src_fin_kernel(
        const float* __restrict__ src, const float* __restrict__ tgt,
        const float* __restrict__ R, const float* __restrict__ t,
        const float* __restrict__ W1, const float* __restrict__ b1,
        const float* __restrict__ W2, const float* __restrict__ b2,
        const float* __restrict__ W3, const float* __restrict__ b3,
        const float* __restrict__ W4, const float* __restrict__ b4,
        float* __restrict__ ws, float* __restrict__ out) {
    __shared__ union {
        unsigned long long runs[8 * 64];
        struct {
            unsigned long long runs2[8 * 64];
            float spts[NS_][CC_];
            float hs[NS_][HH_];
            float sfeat[NS_][DD_];
            float outs[NS_][DD_];
        } sg;
        struct { float th[108][HH_]; float tfeat[NC_][DD_]; } tf;  // 54 KB
    } u;
    __shared__ float bcast[8];
    __shared__ int   nnt216[NC_];
    __shared__ float tall[NC_][CC_];
    __shared__ int   sidx[NS_];
    __shared__ float sdfe[DD_];
    __shared__ float sims[NC_];

    int bk = blockIdx.x;
    int tid = threadIdx.x;
    int w = tid >> 6, lane = tid & 63;
    int bat = bk / KK_, kth = bk % KK_;
    const float* wbuf = ws + OFF_W;
    const int* nntb = (const int*)ws + OFF_NNT;

    // ---------- top-K select -> keypoint out + bcast ----------
    if (w < 8) {
        unsigned long long k4[4];
#pragma unroll
        for (int q = 0; q < 4; ++q) {
            int j = w * 256 + q * 64 + lane;
            k4[q] = ((unsigned long long)(~sortable_f32(wbuf[bat * NN_ + j])) << 32) | (unsigned)j;
        }
        unsigned long long m1 = merge_keep_min64(wave_sort64_asc(k4[0], lane),
                                                 wave_sort64_asc(k4[1], lane), lane);
        unsigned long long m2 = merge_keep_min64(wave_sort64_asc(k4[2], lane),
                                                 wave_sort64_asc(k4[3], lane), lane);
        u.runs[w * 64 + lane] = merge_keep_min64(m1, m2, lane);
    }
    __syncthreads();
#pragma unroll
    for (int lvl = 4; lvl >= 1; lvl >>= 1) {
        unsigned long long r = 0;
        if (w < lvl) r = merge_keep_min64(u.runs[w * 64 + lane], u.runs[(w + lvl) * 64 + lane], lane);
        __syncthreads();
        if (w < lvl) u.runs[w * 64 + lane] = r;
        __syncthreads();
    }
    if (tid == 0) {
        int bi = (int)(u.runs[kth] & 0xFFFFFFFFu);
        float c3[3];
#pragma unroll
        for (int c = 0; c < CC_; ++c) {
            float v = src[(bat * CC_ + c) * NN_ + bi];
            out[bk * CC_ + c] = v;
            if (c < 3) c3[c] = v;
        }
        bcast[0] = c3[0]; bcast[1] = c3[1]; bcast[2] = c3[2];
#pragma unroll
        for (int i = 0; i < 3; ++i) {
#pragma clang fp contract(off)
            bcast[3 + i] = ((R[i * 3 + 0] * c3[0] + R[i * 3 + 1] * c3[1]) + R[i * 3 + 2] * c3[2]) + t[i];
        }
    }
    __syncthreads();

    // ---------- src grouping ----------
    float c0 = bcast[0], c1 = bcast[1], c2 = bcast[2];
    float aa;
    {
#pragma clang fp contract(off)
        aa = (c0 * c0 + c1 * c1) + c2 * c2;
    }
    float m2x = -2.0f * c0, m2y = -2.0f * c1, m2z = -2.0f * c2;
    if (w < 8) {
        unsigned long long k4[4];
#pragma unroll
        for (int q = 0; q < 4; ++q) {
            int j = w * 256 + q * 64 + lane;
            float px = src[(bat * CC_ + 0) * NN_ + j];
            float py = src[(bat * CC_ + 1) * NN_ + j];
            float pz = src[(bat * CC_ + 2) * NN_ + j];
            float d2;
            {
#pragma clang fp contract(off)
                float pw = (px * px + py * py) + pz * pz;
                d2 = (aa + pw) + ((m2x * px + m2y * py) + m2z * pz);
            }
            k4[q] = ((unsigned long long)sortable_f32(d2) << 32) | (unsigned)j;
        }
        unsigned long long m1 = merge_keep_min64(wave_sort64_asc(k4[0], lane),
                                                 wave_sort64_asc(k4[1], lane), lane);
        unsigned long long m2 = merge_keep_min64(wave_sort64_asc(k4[2], lane),
                                                 wave_sort64_asc(k4[3], lane), lane);
        u.sg.runs2[w * 64 + lane] = merge_keep_min64(m1, m2, lane);
    }
    __syncthreads();
#pragma unroll
    for (int lvl = 4; lvl >= 1; lvl >>= 1) {
        unsigned long long r = 0;
        if (w < lvl) r = merge_keep_min64(u.sg.runs2[w * 64 + lane], u.sg.runs2[(w + lvl) * 64 + lane], lane);
        __syncthreads();
        if (w < lvl) u.sg.runs2[w * 64 + lane] = r;
        __syncthreads();
    }
    if (tid < NS_) {
        unsigned long long key = u.sg.runs2[tid];
        unsigned long long key0 = u.sg.runs2[0];
        float dd = unsortable_f32((unsigned)(key >> 32));
        sidx[tid] = (dd <= 1.0f) ? (int)(key & 0xFFFFFFFFu) : (int)(key0 & 0xFFFFFFFFu);  // R^2=1
    }
    __syncthreads();
    for (int idx = tid; idx < NS_ * CC_; idx += 576) {
        int pt = idx / CC_, c = idx % CC_;
        u.sg.spts[pt][c] = src[(bat * CC_ + c) * NN_ + sidx[pt]];
    }
    __syncthreads();
    for (int idx = tid; idx < NS_ * HH_; idx += 576) {
        int pt = idx >> 6, tt = idx & 63;
        float s = b1[tt];
#pragma unroll
        for (int c = 0; c < CC_; ++c) s += u.sg.spts[pt][c] * W1[c * HH_ + tt];
        u.sg.hs[pt][tt] = fmaxf(s, 0.f);
    }
    __syncthreads();
    for (int idx = tid; idx < NS_ * DD_; idx += 576) {
        int pt = idx >> 5, d = idx & 31;
        float s = b2[d];
#pragma unroll 8
        for (int tt = 0; tt < HH_; ++tt) s += u.sg.hs[pt][tt] * W2[tt * DD_ + d];
        u.sg.sfeat[pt][d] = fmaxf(s, 0.f);
    }
    __syncthreads();
    if (w < 8) {
#pragma unroll
        for (int ss = 0; ss < 4; ++ss) {
            int s = w * 4 + ss;
            float r0 = u.sg.spts[s][0] - c0, r1 = u.sg.spts[s][1] - c1, r2 = u.sg.spts[s][2] - c2;
            float acc = b3[lane] + r0 * W3[0 * HH_ + lane] + r1 * W3[1 * HH_ + lane] + r2 * W3[2 * HH_ + lane];
#pragma unroll 8
            for (int d = 0; d < DD_; ++d) acc += u.sg.sfeat[s][d] * W3[(3 + d) * HH_ + lane];
            u.sg.hs[s][lane] = fmaxf(acc, 0.f);
        }
    }
    __syncthreads();
    for (int idx = tid; idx < NS_ * DD_; idx += 576) {
        int s = idx >> 5, d = idx & 31;
        float o = b4[d];
#pragma unroll 8
        for (int tt = 0; tt < HH_; ++tt) o += u.sg.hs[s][tt] * W4[tt * DD_ + d];
        u.sg.outs[s][d] = fmaxf(o, 0.f);
    }
    __syncthreads();
    if (tid < DD_) {
        float m = -INFINITY;
#pragma unroll 8
        for (int s = 0; s < NS_; ++s) m = fmaxf(m, u.sg.outs[s][tid]);
        sdfe[tid] = m;
    }
    __syncthreads();

    // ---------- pull NNT (normal loads; cand_kernel synced by kernel boundary) ----------
    for (int idx = tid; idx < NC_; idx += 576) nnt216[idx] = nntb[bk * NC_ + idx];
    __syncthreads();

    // ---------- tgt feats for the 216 chosen NN ----------
    for (int idx = tid; idx < NC_ * CC_; idx += 576) {
        int pt = idx / CC_, c = idx % CC_;
        tall[pt][c] = tgt[(bat * CC_ + c) * NN_ + nnt216[pt]];
    }
    __syncthreads();
    for (int ch = 0; ch < 2; ++ch) {
        for (int idx = tid; idx < 108 * HH_; idx += 576) {
            int pl = idx >> 6, tt = idx & 63;
            int pt = ch * 108 + pl;
            float s = b1[tt];
#pragma unroll
            for (int c = 0; c < CC_; ++c) s += tall[pt][c] * W1[c * HH_ + tt];
            u.tf.th[pl][tt] = fmaxf(s, 0.f);
        }
        __syncthreads();
        for (int idx = tid; idx < 108 * DD_; idx += 576) {
            int pl = idx >> 5, d = idx & 31;
            int pt = ch * 108 + pl;
            float s = b2[d];
#pragma unroll 8
            for (int tt = 0; tt < HH_; ++tt) s += u.tf.th[pl][tt] * W2[tt * DD_ + d];
            u.tf.tfeat[pt][d] = fmaxf(s, 0.f);
        }
        __syncthreads();
    }

    // ---------- per-candidate MLP + sim + softmax + vcp ----------
    float x0 = bcast[3], x1 = bcast[4], x2 = bcast[5];
    if (tid < NC_) {
        int c = tid;
        int ix = c / 36, iy = (c / 6) % 6, iz = c % 6;
        float cx = x0 + (ix * 0.4f - 1.0f);
        float cy = x1 + (iy * 0.4f - 1.0f);
        float cz = x2 + (iz * 0.4f - 1.0f);
        float x[3 + DD_];
        x[0] = tall[c][0] - cx; x[1] = tall[c][1] - cy; x[2] = tall[c][2] - cz;
#pragma unroll
        for (int d = 0; d < DD_; ++d) x[3 + d] = u.tf.tfeat[c][d];
        float o[DD_];
#pragma unroll
        for (int d = 0; d < DD_; ++d) o[d] = b4[d];
        for (int tt = 0; tt < HH_; ++tt) {
            float acc = b3[tt];
#pragma unroll
            for (int cc = 0; cc < 3 + DD_; ++cc) acc += x[cc] * W3[cc * HH_ + tt];
            float ht = fmaxf(acc, 0.f);
#pragma unroll
            for (int d = 0; d < DD_; ++d) o[d] += ht * W4[tt * DD_ + d];
        }
        float sim = 0.f;
#pragma unroll
        for (int d = 0; d < DD_; ++d) sim += fmaxf(o[d], 0.f) * sdfe[d];
        sims[c] = sim;
    }
    __syncthreads();
    if (tid < 64) {
        float m = -INFINITY;
        for (int c = lane; c < NC_; c += 64) m = fmaxf(m, sims[c]);
#pragma unroll
        for (int sh = 32; sh; sh >>= 1) m = fmaxf(m, __shfl_xor(m, sh));
        float se = 0.f, v0 = 0.f, v1 = 0.f, v2 = 0.f;
        for (int c = lane; c < NC_; c += 64) {
            float e = expf(sims[c] - m);
            int ix = c / 36, iy = (c / 6) % 6, iz = c % 6;
            se += e;
            v0 += e * (x0 + (ix * 0.4f - 1.0f));
            v1 += e * (x1 + (iy * 0.4f - 1.0f));
            v2 += e * (x2 + (iz * 0.4f - 1.0f));
        }
#pragma unroll
        for (int sh = 32; sh; sh >>= 1) {
            se += __shfl_xor(se, sh);
            v0 += __shfl_xor(v0, sh);
            v1 += __shfl_xor(v1, sh);
            v2 += __shfl_xor(v2, sh);
        }
        if (lane == 0) {
            float inv = 1.0f / se;
            float* oo = out + BB_ * KK_ * CC_ + bk * 3;
            oo[0] = v0 * inv;
            oo[1] = v1 * inv;
            oo[2] = v2 * inv;
        }
    }
}

extern "C" void kernel_launch(void* const* d_in, const int* in_sizes, int n_in,
                              void* d_out, int out_size, void* d_ws, size_t ws_size,
                              hipStream_t stream) {
    const float* src = (const float*)d_in[0];
    const float* tgt = (const float*)d_in[1];
    const float* R   = (const float*)d_in[2];
    const float* t   = (const float*)d_in[3];
    const float* W1  = (const float*)d_in[4];
    const float* b1  = (const float*)d_in[5];
    const float* W2  = (const float*)d_in[6];
    const float* b2  = (const float*)d_in[7];
    const float* Wwl = (const float*)d_in[8];
    const float* bwl = (const float*)d_in[9];
    const float* W3  = (const float*)d_in[10];
    const float* b3  = (const float*)d_in[11];
    const float* W4  = (const float*)d_in[12];
    const float* b4  = (const float*)d_in[13];
    float* ws  = (float*)d_ws;
    float* out = (float*)d_out;

    fe_w_kernel<<<16, 256, 0, stream>>>(src, W1, b1, W2, b2, Wwl, bwl, ws);
    cand_kernel<<<2 * BB_ * KK_, 576, 0, stream>>>(src, tgt, R, t, ws);
    src_fin_kernel<<<BB_ * KK_, 576, 0, stream>>>(src, tgt, R, t, W1, b1, W2, b2,
                                                  W3, b3, W4, b4, ws, out);
}

// Round 12
// 92.425 us; speedup vs baseline: 1.7821x; 1.1931x over previous
//
#include <hip/hip_runtime.h>
#include <math.h>

// Problem constants
#define BB_ 2      // batch
#define CC_ 6      // channels
#define NN_ 2048   // points
#define KK_ 64     // keypoints
#define NS_ 32     // neighbors
#define DD_ 32     // feat dim
#define NC_ 216    // candidate grid (6^3)
#define HH_ 64     // hidden dim

// ws layout (element units)
#define OFF_W      0        // 4096 floats
#define OFF_NNT    4096     // 27648 ints (int* view)
#define OFF_XF     31744    // 384 floats (xform per bk)
#define OFF_SDFE   32128    // 4096 floats

// Order-preserving bijection float -> uint32 (ascending)
__device__ __forceinline__ unsigned sortable_f32(float f) {
    unsigned u = __float_as_uint(f);
    return (u & 0x80000000u) ? ~u : (u | 0x80000000u);
}
__device__ __forceinline__ float unsortable_f32(unsigned s) {
    unsigned u = (s & 0x80000000u) ? (s ^ 0x80000000u) : ~s;
    return __uint_as_float(u);
}

__device__ __forceinline__ unsigned long long wave_sort64_asc(unsigned long long key, int lane) {
#pragma unroll
    for (int k = 2; k <= 64; k <<= 1) {
#pragma unroll
        for (int j = k >> 1; j > 0; j >>= 1) {
            unsigned long long other = __shfl_xor(key, j);
            bool lower = (lane & j) == 0;
            bool asc = (lane & k) == 0;
            bool takemin = (lower == asc);
            unsigned long long mn = key < other ? key : other;
            unsigned long long mx = key < other ? other : key;
            key = takemin ? mn : mx;
        }
    }
    return key;
}

__device__ __forceinline__ unsigned long long merge_keep_min64(unsigned long long a, unsigned long long b, int lane) {
    unsigned long long br = __shfl(b, 63 - lane);
    unsigned long long m = a < br ? a : br;
#pragma unroll
    for (int j = 32; j > 0; j >>= 1) {
        unsigned long long other = __shfl_xor(m, j);
        bool lower = (lane & j) == 0;
        unsigned long long mn = m < other ? m : other;
        unsigned long long mx = m < other ? other : m;
        m = lower ? mn : mx;
    }
    return m;
}

// -------------------- K1: keypoint weights only --------------------
__global__ void fe_w_kernel(const float* __restrict__ src,
                            const float* __restrict__ W1, const float* __restrict__ b1,
                            const float* __restrict__ W2, const float* __restrict__ b2,
                            const float* __restrict__ Wwl, const float* __restrict__ bwl,
                            float* __restrict__ ws) {
    int g = blockIdx.x * blockDim.x + threadIdx.x;     // 0..4095
    int b = g / NN_, n = g % NN_;
    float x[CC_];
#pragma unroll
    for (int c = 0; c < CC_; ++c) x[c] = src[(b * CC_ + c) * NN_ + n];
    float h[HH_];
#pragma unroll
    for (int t = 0; t < HH_; ++t) {
        float s = b1[t];
#pragma unroll
        for (int c = 0; c < CC_; ++c) s += x[c] * W1[c * HH_ + t];
        h[t] = fmaxf(s, 0.f);
    }
    float wsum = 0.f;
#pragma unroll 4
    for (int d = 0; d < DD_; ++d) {
        float s = b2[d];
#pragma unroll
        for (int t = 0; t < HH_; ++t) s += h[t] * W2[t * DD_ + d];
        s = fmaxf(s, 0.f);
        wsum += s * Wwl[d];
    }
    (ws + OFF_W)[g] = wsum + bwl[0];
}

// -------------------- K2: cand role (256 blocks) + src role (128 blocks) ----
__global__ __launch_bounds__(576) void mid3_kernel(
        const float* __restrict__ src, const float* __restrict__ tgt,
        const float* __restrict__ R, const float* __restrict__ t,
        const float* __restrict__ W1, const float* __restrict__ b1,
        const float* __restrict__ W2, const float* __restrict__ b2,
        const float* __restrict__ W3, const float* __restrict__ b3,
        const float* __restrict__ W4, const float* __restrict__ b4,
        float* __restrict__ ws, float* __restrict__ out) {
    __shared__ union {
        unsigned long long runs[8 * 64];                 // 4 KB (select)
        float4 pk[NN_];                                  // 32 KB (cand)
        struct {
            unsigned long long runs2[8 * 64];
            float spts[NS_][CC_];
            float hs[NS_][HH_];
            float sfeat[NS_][DD_];
            float outs[NS_][DD_];
        } sg;                                            // ~20 KB (src)
    } u;
    __shared__ float bcast[8];
    __shared__ int   sidx[NS_];
    __shared__ float sdfe[DD_];

    int blk = blockIdx.x;
    int tid = threadIdx.x;
    int w = tid >> 6, lane = tid & 63;
    bool cand_role = (blk < 2 * BB_ * KK_);
    int bk = cand_role ? (blk >> 1) : (blk - 2 * BB_ * KK_);
    int bat = bk / KK_, kth = bk % KK_;
    const float* wbuf = ws + OFF_W;
    int* nntb = (int*)ws + OFF_NNT;

    // ---------- per-block top-K select ----------
    if (w < 8) {
        unsigned long long k4[4];
#pragma unroll
        for (int q = 0; q < 4; ++q) {
            int j = w * 256 + q * 64 + lane;
            k4[q] = ((unsigned long long)(~sortable_f32(wbuf[bat * NN_ + j])) << 32) | (unsigned)j;
        }
        unsigned long long m1 = merge_keep_min64(wave_sort64_asc(k4[0], lane),
                                                 wave_sort64_asc(k4[1], lane), lane);
        unsigned long long m2 = merge_keep_min64(wave_sort64_asc(k4[2], lane),
                                                 wave_sort64_asc(k4[3], lane), lane);
        u.runs[w * 64 + lane] = merge_keep_min64(m1, m2, lane);
    }
    __syncthreads();
#pragma unroll
    for (int lvl = 4; lvl >= 1; lvl >>= 1) {
        unsigned long long r = 0;
        if (w < lvl) r = merge_keep_min64(u.runs[w * 64 + lane], u.runs[(w + lvl) * 64 + lane], lane);
        __syncthreads();
        if (w < lvl) u.runs[w * 64 + lane] = r;
        __syncthreads();
    }
    if (tid == 0) {
        int bi = (int)(u.runs[kth] & 0xFFFFFFFFu);
        float c3[3];
#pragma unroll
        for (int c = 0; c < CC_; ++c) {
            float v = src[(bat * CC_ + c) * NN_ + bi];
            if (!cand_role) out[bk * CC_ + c] = v;       // one writer per bk
            if (c < 3) c3[c] = v;
        }
        bcast[0] = c3[0]; bcast[1] = c3[1]; bcast[2] = c3[2];
#pragma unroll
        for (int i = 0; i < 3; ++i) {
            float xfi;
            {
#pragma clang fp contract(off)
                xfi = ((R[i * 3 + 0] * c3[0] + R[i * 3 + 1] * c3[1]) + R[i * 3 + 2] * c3[2]) + t[i];
            }
            bcast[3 + i] = xfi;
            if (!cand_role) (ws + OFF_XF)[bk * 3 + i] = xfi;
        }
    }
    __syncthreads();

    if (cand_role) {
        // ---------- cand role: NN for 18 xy-groups ----------
        int half = blk & 1;
        for (int j = tid; j < NN_; j += 576) {
            float px = tgt[(bat * CC_ + 0) * NN_ + j];
            float py = tgt[(bat * CC_ + 1) * NN_ + j];
            float pz = tgt[(bat * CC_ + 2) * NN_ + j];
            float pw;
            {
#pragma clang fp contract(off)
                pw = (px * px + py * py) + pz * pz;
            }
            u.pk[j ^ ((j >> 6) & 7)] = make_float4(px, py, pz, pw);
        }
        float x0 = bcast[3], x1 = bcast[4], x2 = bcast[5];
        __syncthreads();

        int lg = tid >> 5;                       // 0..17
        int chunk = tid & 31;
        int grp = half * 18 + lg;                // 0..35 = ix*6+iy
        int ix = grp / 6, iy = grp % 6;
        float cx = x0 + (ix * 0.4f - 1.0f);
        float cy = x1 + (iy * 0.4f - 1.0f);
        float cxy2;
        {
#pragma clang fp contract(off)
            cxy2 = cx * cx + cy * cy;
        }
        float m2x = -2.0f * cx, m2y = -2.0f * cy;
        float aaz[6], m2z[6];
#pragma unroll
        for (int z = 0; z < 6; ++z) {
            float cz = x2 + (z * 0.4f - 1.0f);
            {
#pragma clang fp contract(off)
                aaz[z] = cxy2 + cz * cz;
            }
            m2z[z] = -2.0f * cz;
        }
        float bv[6];
        int bi6[6];
#pragma unroll
        for (int z = 0; z < 6; ++z) { bv[z] = INFINITY; bi6[z] = 0; }
        int base = chunk * 64;
        int sw = chunk & 7;
        for (int i = 0; i < 64; ++i) {
            int j = base + i;                    // ascending j -> first-index ties
            float4 p = u.pk[base + (i ^ sw)];    // slot(j) for j=base+i
            float txy;
            {
#pragma clang fp contract(off)
                txy = m2x * p.x + m2y * p.y;
            }
#pragma unroll
            for (int z = 0; z < 6; ++z) {
                float d2;
                {
#pragma clang fp contract(off)
                    d2 = (aaz[z] + p.w) + (txy + m2z[z] * p.z);
                }
                if (d2 < bv[z]) { bv[z] = d2; bi6[z] = j; }
            }
        }
#pragma unroll
        for (int z = 0; z < 6; ++z) {
            unsigned long long key = ((unsigned long long)sortable_f32(bv[z]) << 32) | (unsigned)bi6[z];
#pragma unroll
            for (int m = 1; m <= 16; m <<= 1) {
                unsigned long long other = __shfl_xor(key, m);
                key = other < key ? other : key;
            }
            if (chunk == 0) nntb[bk * NC_ + grp * 6 + z] = (int)(key & 0xFFFFFFFFu);
        }
    } else {
        // ---------- src role: grouping + on-demand feats + dfe + max ----------
        float c0 = bcast[0], c1 = bcast[1], c2 = bcast[2];
        float aa;
        {
#pragma clang fp contract(off)
            aa = (c0 * c0 + c1 * c1) + c2 * c2;
        }
        float m2x = -2.0f * c0, m2y = -2.0f * c1, m2z = -2.0f * c2;
        if (w < 8) {
            unsigned long long k4[4];
#pragma unroll
            for (int q = 0; q < 4; ++q) {
                int j = w * 256 + q * 64 + lane;
                float px = src[(bat * CC_ + 0) * NN_ + j];
                float py = src[(bat * CC_ + 1) * NN_ + j];
                float pz = src[(bat * CC_ + 2) * NN_ + j];
                float d2;
                {
#pragma clang fp contract(off)
                    float pw = (px * px + py * py) + pz * pz;
                    d2 = (aa + pw) + ((m2x * px + m2y * py) + m2z * pz);
                }
                k4[q] = ((unsigned long long)sortable_f32(d2) << 32) | (unsigned)j;
            }
            unsigned long long m1 = merge_keep_min64(wave_sort64_asc(k4[0], lane),
                                                     wave_sort64_asc(k4[1], lane), lane);
            unsigned long long m2 = merge_keep_min64(wave_sort64_asc(k4[2], lane),
                                                     wave_sort64_asc(k4[3], lane), lane);
            u.sg.runs2[w * 64 + lane] = merge_keep_min64(m1, m2, lane);
        }
        __syncthreads();
#pragma unroll
        for (int lvl = 4; lvl >= 1; lvl >>= 1) {
            unsigned long long r = 0;
            if (w < lvl) r = merge_keep_min64(u.sg.runs2[w * 64 + lane], u.sg.runs2[(w + lvl) * 64 + lane], lane);
            __syncthreads();
            if (w < lvl) u.sg.runs2[w * 64 + lane] = r;
            __syncthreads();
        }
        if (tid < NS_) {
            unsigned long long key = u.sg.runs2[tid];
            unsigned long long key0 = u.sg.runs2[0];
            float dd = unsortable_f32((unsigned)(key >> 32));
            sidx[tid] = (dd <= 1.0f) ? (int)(key & 0xFFFFFFFFu) : (int)(key0 & 0xFFFFFFFFu);  // R^2=1
        }
        __syncthreads();
        for (int idx = tid; idx < NS_ * CC_; idx += 576) {
            int pt = idx / CC_, c = idx % CC_;
            u.sg.spts[pt][c] = src[(bat * CC_ + c) * NN_ + sidx[pt]];
        }
        __syncthreads();
        for (int idx = tid; idx < NS_ * HH_; idx += 576) {
            int pt = idx >> 6, tt = idx & 63;
            float s = b1[tt];
#pragma unroll
            for (int c = 0; c < CC_; ++c) s += u.sg.spts[pt][c] * W1[c * HH_ + tt];
            u.sg.hs[pt][tt] = fmaxf(s, 0.f);
        }
        __syncthreads();
        for (int idx = tid; idx < NS_ * DD_; idx += 576) {
            int pt = idx >> 5, d = idx & 31;
            float s = b2[d];
#pragma unroll 8
            for (int tt = 0; tt < HH_; ++tt) s += u.sg.hs[pt][tt] * W2[tt * DD_ + d];
            u.sg.sfeat[pt][d] = fmaxf(s, 0.f);
        }
        __syncthreads();
        if (w < 8) {
#pragma unroll
            for (int ss = 0; ss < 4; ++ss) {
                int s = w * 4 + ss;
                float r0 = u.sg.spts[s][0] - c0, r1 = u.sg.spts[s][1] - c1, r2 = u.sg.spts[s][2] - c2;
                float acc = b3[lane] + r0 * W3[0 * HH_ + lane] + r1 * W3[1 * HH_ + lane] + r2 * W3[2 * HH_ + lane];
#pragma unroll 8
                for (int d = 0; d < DD_; ++d) acc += u.sg.sfeat[s][d] * W3[(3 + d) * HH_ + lane];
                u.sg.hs[s][lane] = fmaxf(acc, 0.f);
            }
        }
        __syncthreads();
        for (int idx = tid; idx < NS_ * DD_; idx += 576) {
            int s = idx >> 5, d = idx & 31;
            float o = b4[d];
#pragma unroll 8
            for (int tt = 0; tt < HH_; ++tt) o += u.sg.hs[s][tt] * W4[tt * DD_ + d];
            u.sg.outs[s][d] = fmaxf(o, 0.f);
        }
        __syncthreads();
        if (tid < DD_) {
            float m = -INFINITY;
#pragma unroll 8
            for (int s = 0; s < NS_; ++s) m = fmaxf(m, u.sg.outs[s][tid]);
            (ws + OFF_SDFE)[bk * DD_ + tid] = m;
        }
    }
}

// -------------------- K3: per-candidate MLP + sim + softmax + vcp --------------------
// 128 blocks x 256 threads; thread-per-candidate; all arrays in registers.
__global__ __launch_bounds__(256) void simvcp3_kernel(
        const float* __restrict__ tgt,
        const float* __restrict__ W1, const float* __restrict__ b1,
        const float* __restrict__ W2, const float* __restrict__ b2,
        const float* __restrict__ W3, const float* __restrict__ b3,
        const float* __restrict__ W4, const float* __restrict__ b4,
        const float* __restrict__ ws, float* __restrict__ out) {
    __shared__ float sims[NC_];
    __shared__ float sdfe_s[DD_];
    int bk = blockIdx.x;
    int bat = bk / KK_;
    int tid = threadIdx.x;
    const float* xf = ws + OFF_XF + bk * 3;
    float x0 = xf[0], x1 = xf[1], x2 = xf[2];
    if (tid < DD_) sdfe_s[tid] = (ws + OFF_SDFE)[bk * DD_ + tid];
    __syncthreads();
    if (tid < NC_) {
        int c = tid;
        int ix = c / 36, iy = (c / 6) % 6, iz = c % 6;
        float cx = x0 + (ix * 0.4f - 1.0f);
        float cy = x1 + (iy * 0.4f - 1.0f);
        float cz = x2 + (iz * 0.4f - 1.0f);
        int bi = ((const int*)ws)[OFF_NNT + bk * NC_ + c];
        float xc[CC_];
#pragma unroll
        for (int ch = 0; ch < CC_; ++ch) xc[ch] = tgt[(bat * CC_ + ch) * NN_ + bi];
        // tgt fe on demand (identical arithmetic to fe_kernel)
        float h[HH_];
#pragma unroll
        for (int tt = 0; tt < HH_; ++tt) {
            float s = b1[tt];
#pragma unroll
            for (int ch = 0; ch < CC_; ++ch) s += xc[ch] * W1[ch * HH_ + tt];
            h[tt] = fmaxf(s, 0.f);
        }
        float x[3 + DD_];
        x[0] = xc[0] - cx; x[1] = xc[1] - cy; x[2] = xc[2] - cz;
#pragma unroll 4
        for (int d = 0; d < DD_; ++d) {
            float s = b2[d];
#pragma unroll
            for (int tt = 0; tt < HH_; ++tt) s += h[tt] * W2[tt * DD_ + d];
            x[3 + d] = fmaxf(s, 0.f);
        }
        float o[DD_];
#pragma unroll
        for (int d = 0; d < DD_; ++d) o[d] = b4[d];
        for (int tt = 0; tt < HH_; ++tt) {
            float acc = b3[tt];
#pragma unroll
            for (int cc = 0; cc < 3 + DD_; ++cc) acc += x[cc] * W3[cc * HH_ + tt];
            float ht = fmaxf(acc, 0.f);
#pragma unroll
            for (int d = 0; d < DD_; ++d) o[d] += ht * W4[tt * DD_ + d];
        }
        float sim = 0.f;
#pragma unroll
        for (int d = 0; d < DD_; ++d) sim += fmaxf(o[d], 0.f) * sdfe_s[d];
        sims[c] = sim;
    }
    __syncthreads();
    if (tid < 64) {
        int lane = tid;
        float m = -INFINITY;
        for (int c = lane; c < NC_; c += 64) m = fmaxf(m, sims[c]);
#pragma unroll
        for (int sh = 32; sh; sh >>= 1) m = fmaxf(m, __shfl_xor(m, sh));
        float se = 0.f, v0 = 0.f, v1 = 0.f, v2 = 0.f;
        for (int c = lane; c < NC_; c += 64) {
            float e = expf(sims[c] - m);
            int ix = c / 36, iy = (c / 6) % 6, iz = c % 6;
            se += e;
            v0 += e * (x0 + (ix * 0.4f - 1.0f));
            v1 += e * (x1 + (iy * 0.4f - 1.0f));
            v2 += e * (x2 + (iz * 0.4f - 1.0f));
        }
#pragma unroll
        for (int sh = 32; sh; sh >>= 1) {
            se += __shfl_xor(se, sh);
            v0 += __shfl_xor(v0, sh);
            v1 += __shfl_xor(v1, sh);
            v2 += __shfl_xor(v2, sh);
        }
        if (lane == 0) {
            float inv = 1.0f / se;
            float* oo = out + BB_ * KK_ * CC_ + bk * 3;
            oo[0] = v0 * inv;
            oo[1] = v1 * inv;
            oo[2] = v2 * inv;
        }
    }
}

extern "C" void kernel_launch(void* const* d_in, const int* in_sizes, int n_in,
                              void* d_out, int out_size, void* d_ws, size_t ws_size,
                              hipStream_t stream) {
    const float* src = (const float*)d_in[0];
    const float* tgt = (const float*)d_in[1];
    const float* R   = (const float*)d_in[2];
    const float* t   = (const float*)d_in[3];
    const float* W1  = (const float*)d_in[4];
    const float* b1  = (const float*)d_in[5];
    const float* W2  = (const float*)d_in[6];
    const float* b2  = (const float*)d_in[7];
    const float* Wwl = (const float*)d_in[8];
    const float* bwl = (const float*)d_in[9];
    const float* W3  = (const float*)d_in[10];
    const float* b3  = (const float*)d_in[11];
    const float* W4  = (const float*)d_in[12];
    const float* b4  = (const float*)d_in[13];
    float* ws  = (float*)d_ws;
    float* out = (float*)d_out;

    fe_w_kernel<<<16, 256, 0, stream>>>(src, W1, b1, W2, b2, Wwl, bwl, ws);
    mid3_kernel<<<3 * BB_ * KK_, 576, 0, stream>>>(src, tgt, R, t, W1, b1, W2, b2,
                                                   W3, b3, W4, b4, ws, out);
    simvcp3_kernel<<<BB_ * KK_, 256, 0, stream>>>(tgt, W1, b1, W2, b2,
                                                  W3, b3, W4, b4, ws, out);
}

// Round 13
// 91.814 us; speedup vs baseline: 1.7939x; 1.0067x over previous
//
#include <hip/hip_runtime.h>
#include <math.h>

// Problem constants
#define BB_ 2      // batch
#define CC_ 6      // channels
#define NN_ 2048   // points
#define KK_ 64     // keypoints
#define NS_ 32     // neighbors
#define DD_ 32     // feat dim
#define NC_ 216    // candidate grid (6^3)
#define HH_ 64     // hidden dim

// ws layout (element units)
#define OFF_W      0        // 4096 floats
#define OFF_NNT    4096     // 27648 ints (int* view)
#define OFF_XF     31744    // 384 floats (xform per bk)
#define OFF_SDFE   32128    // 4096 floats

// Order-preserving bijection float -> uint32 (ascending)
__device__ __forceinline__ unsigned sortable_f32(float f) {
    unsigned u = __float_as_uint(f);
    return (u & 0x80000000u) ? ~u : (u | 0x80000000u);
}
__device__ __forceinline__ float unsortable_f32(unsigned s) {
    unsigned u = (s & 0x80000000u) ? (s ^ 0x80000000u) : ~s;
    return __uint_as_float(u);
}

__device__ __forceinline__ unsigned long long wave_sort64_asc(unsigned long long key, int lane) {
#pragma unroll
    for (int k = 2; k <= 64; k <<= 1) {
#pragma unroll
        for (int j = k >> 1; j > 0; j >>= 1) {
            unsigned long long other = __shfl_xor(key, j);
            bool lower = (lane & j) == 0;
            bool asc = (lane & k) == 0;
            bool takemin = (lower == asc);
            unsigned long long mn = key < other ? key : other;
            unsigned long long mx = key < other ? other : key;
            key = takemin ? mn : mx;
        }
    }
    return key;
}

__device__ __forceinline__ unsigned long long merge_keep_min64(unsigned long long a, unsigned long long b, int lane) {
    unsigned long long br = __shfl(b, 63 - lane);
    unsigned long long m = a < br ? a : br;
#pragma unroll
    for (int j = 32; j > 0; j >>= 1) {
        unsigned long long other = __shfl_xor(m, j);
        bool lower = (lane & j) == 0;
        unsigned long long mn = m < other ? m : other;
        unsigned long long mx = m < other ? other : m;
        m = lower ? mn : mx;
    }
    return m;
}

// -------------------- K1: keypoint weights only --------------------
__global__ void fe_w_kernel(const float* __restrict__ src,
                            const float* __restrict__ W1, const float* __restrict__ b1,
                            const float* __restrict__ W2, const float* __restrict__ b2,
                            const float* __restrict__ Wwl, const float* __restrict__ bwl,
                            float* __restrict__ ws) {
    int g = blockIdx.x * blockDim.x + threadIdx.x;     // 0..4095
    int b = g / NN_, n = g % NN_;
    float x[CC_];
#pragma unroll
    for (int c = 0; c < CC_; ++c) x[c] = src[(b * CC_ + c) * NN_ + n];
    float h[HH_];
#pragma unroll
    for (int t = 0; t < HH_; ++t) {
        float s = b1[t];
#pragma unroll
        for (int c = 0; c < CC_; ++c) s += x[c] * W1[c * HH_ + t];
        h[t] = fmaxf(s, 0.f);
    }
    float wsum = 0.f;
#pragma unroll 4
    for (int d = 0; d < DD_; ++d) {
        float s = b2[d];
#pragma unroll
        for (int t = 0; t < HH_; ++t) s += h[t] * W2[t * DD_ + d];
        s = fmaxf(s, 0.f);
        wsum += s * Wwl[d];
    }
    (ws + OFF_W)[g] = wsum + bwl[0];
}

// -------------------- K2: cand role (256 blocks) + src role (128 blocks) ----
__global__ __launch_bounds__(576) void mid3_kernel(
        const float* __restrict__ src, const float* __restrict__ tgt,
        const float* __restrict__ R, const float* __restrict__ t,
        const float* __restrict__ W1, const float* __restrict__ b1,
        const float* __restrict__ W2, const float* __restrict__ b2,
        const float* __restrict__ W3, const float* __restrict__ b3,
        const float* __restrict__ W4, const float* __restrict__ b4,
        float* __restrict__ ws, float* __restrict__ out) {
    __shared__ union {
        unsigned long long runs[8 * 64];                 // 4 KB (select)
        float4 pk[NN_];                                  // 32 KB (cand)
        struct {
            unsigned long long runs2[8 * 64];
            float spts[NS_][CC_];
            float hs[NS_][HH_];
            float sfeat[NS_][DD_];
            float outs[NS_][DD_];
        } sg;                                            // ~20 KB (src)
    } u;
    __shared__ float bcast[8];
    __shared__ int   sidx[NS_];

    int blk = blockIdx.x;
    int tid = threadIdx.x;
    int w = tid >> 6, lane = tid & 63;
    bool cand_role = (blk < 2 * BB_ * KK_);
    int bk = cand_role ? (blk >> 1) : (blk - 2 * BB_ * KK_);
    int bat = bk / KK_, kth = bk % KK_;
    const float* wbuf = ws + OFF_W;
    int* nntb = (int*)ws + OFF_NNT;

    // ---------- per-block top-K select ----------
    if (w < 8) {
        unsigned long long k4[4];
#pragma unroll
        for (int q = 0; q < 4; ++q) {
            int j = w * 256 + q * 64 + lane;
            k4[q] = ((unsigned long long)(~sortable_f32(wbuf[bat * NN_ + j])) << 32) | (unsigned)j;
        }
        unsigned long long m1 = merge_keep_min64(wave_sort64_asc(k4[0], lane),
                                                 wave_sort64_asc(k4[1], lane), lane);
        unsigned long long m2 = merge_keep_min64(wave_sort64_asc(k4[2], lane),
                                                 wave_sort64_asc(k4[3], lane), lane);
        u.runs[w * 64 + lane] = merge_keep_min64(m1, m2, lane);
    }
    __syncthreads();
#pragma unroll
    for (int lvl = 4; lvl >= 1; lvl >>= 1) {
        unsigned long long r = 0;
        if (w < lvl) r = merge_keep_min64(u.runs[w * 64 + lane], u.runs[(w + lvl) * 64 + lane], lane);
        __syncthreads();
        if (w < lvl) u.runs[w * 64 + lane] = r;
        __syncthreads();
    }
    if (tid == 0) {
        int bi = (int)(u.runs[kth] & 0xFFFFFFFFu);
        float c3[3];
#pragma unroll
        for (int c = 0; c < CC_; ++c) {
            float v = src[(bat * CC_ + c) * NN_ + bi];
            if (!cand_role) out[bk * CC_ + c] = v;       // one writer per bk
            if (c < 3) c3[c] = v;
        }
        bcast[0] = c3[0]; bcast[1] = c3[1]; bcast[2] = c3[2];
#pragma unroll
        for (int i = 0; i < 3; ++i) {
            float xfi;
            {
#pragma clang fp contract(off)
                xfi = ((R[i * 3 + 0] * c3[0] + R[i * 3 + 1] * c3[1]) + R[i * 3 + 2] * c3[2]) + t[i];
            }
            bcast[3 + i] = xfi;
            if (!cand_role) (ws + OFF_XF)[bk * 3 + i] = xfi;
        }
    }
    __syncthreads();

    if (cand_role) {
        // ---------- cand role: NN for 18 xy-groups ----------
        int half = blk & 1;
        for (int j = tid; j < NN_; j += 576) {
            float px = tgt[(bat * CC_ + 0) * NN_ + j];
            float py = tgt[(bat * CC_ + 1) * NN_ + j];
            float pz = tgt[(bat * CC_ + 2) * NN_ + j];
            float pw;
            {
#pragma clang fp contract(off)
                pw = (px * px + py * py) + pz * pz;
            }
            u.pk[j ^ ((j >> 6) & 7)] = make_float4(px, py, pz, pw);
        }
        float x0 = bcast[3], x1 = bcast[4], x2 = bcast[5];
        __syncthreads();

        int lg = tid >> 5;                       // 0..17
        int chunk = tid & 31;
        int grp = half * 18 + lg;                // 0..35 = ix*6+iy
        int ix = grp / 6, iy = grp % 6;
        float cx = x0 + (ix * 0.4f - 1.0f);
        float cy = x1 + (iy * 0.4f - 1.0f);
        float cxy2;
        {
#pragma clang fp contract(off)
            cxy2 = cx * cx + cy * cy;
        }
        float m2x = -2.0f * cx, m2y = -2.0f * cy;
        float aaz[6], m2z[6];
#pragma unroll
        for (int z = 0; z < 6; ++z) {
            float cz = x2 + (z * 0.4f - 1.0f);
            {
#pragma clang fp contract(off)
                aaz[z] = cxy2 + cz * cz;
            }
            m2z[z] = -2.0f * cz;
        }
        float bv[6];
        int bi6[6];
#pragma unroll
        for (int z = 0; z < 6; ++z) { bv[z] = INFINITY; bi6[z] = 0; }
        int base = chunk * 64;
        int sw = chunk & 7;
        for (int i = 0; i < 64; ++i) {
            int j = base + i;                    // ascending j -> first-index ties
            float4 p = u.pk[base + (i ^ sw)];    // slot(j) for j=base+i
            float txy;
            {
#pragma clang fp contract(off)
                txy = m2x * p.x + m2y * p.y;
            }
#pragma unroll
            for (int z = 0; z < 6; ++z) {
                float d2;
                {
#pragma clang fp contract(off)
                    d2 = (aaz[z] + p.w) + (txy + m2z[z] * p.z);
                }
                if (d2 < bv[z]) { bv[z] = d2; bi6[z] = j; }
            }
        }
#pragma unroll
        for (int z = 0; z < 6; ++z) {
            unsigned long long key = ((unsigned long long)sortable_f32(bv[z]) << 32) | (unsigned)bi6[z];
#pragma unroll
            for (int m = 1; m <= 16; m <<= 1) {
                unsigned long long other = __shfl_xor(key, m);
                key = other < key ? other : key;
            }
            if (chunk == 0) nntb[bk * NC_ + grp * 6 + z] = (int)(key & 0xFFFFFFFFu);
        }
    } else {
        // ---------- src role: grouping + on-demand feats + dfe + max ----------
        float c0 = bcast[0], c1 = bcast[1], c2 = bcast[2];
        float aa;
        {
#pragma clang fp contract(off)
            aa = (c0 * c0 + c1 * c1) + c2 * c2;
        }
        float m2x = -2.0f * c0, m2y = -2.0f * c1, m2z = -2.0f * c2;
        if (w < 8) {
            unsigned long long k4[4];
#pragma unroll
            for (int q = 0; q < 4; ++q) {
                int j = w * 256 + q * 64 + lane;
                float px = src[(bat * CC_ + 0) * NN_ + j];
                float py = src[(bat * CC_ + 1) * NN_ + j];
                float pz = src[(bat * CC_ + 2) * NN_ + j];
                float d2;
                {
#pragma clang fp contract(off)
                    float pw = (px * px + py * py) + pz * pz;
                    d2 = (aa + pw) + ((m2x * px + m2y * py) + m2z * pz);
                }
                k4[q] = ((unsigned long long)sortable_f32(d2) << 32) | (unsigned)j;
            }
            unsigned long long m1 = merge_keep_min64(wave_sort64_asc(k4[0], lane),
                                                     wave_sort64_asc(k4[1], lane), lane);
            unsigned long long m2 = merge_keep_min64(wave_sort64_asc(k4[2], lane),
                                                     wave_sort64_asc(k4[3], lane), lane);
            u.sg.runs2[w * 64 + lane] = merge_keep_min64(m1, m2, lane);
        }
        __syncthreads();
#pragma unroll
        for (int lvl = 4; lvl >= 1; lvl >>= 1) {
            unsigned long long r = 0;
            if (w < lvl) r = merge_keep_min64(u.sg.runs2[w * 64 + lane], u.sg.runs2[(w + lvl) * 64 + lane], lane);
            __syncthreads();
            if (w < lvl) u.sg.runs2[w * 64 + lane] = r;
            __syncthreads();
        }
        if (tid < NS_) {
            unsigned long long key = u.sg.runs2[tid];
            unsigned long long key0 = u.sg.runs2[0];
            float dd = unsortable_f32((unsigned)(key >> 32));
            sidx[tid] = (dd <= 1.0f) ? (int)(key & 0xFFFFFFFFu) : (int)(key0 & 0xFFFFFFFFu);  // R^2=1
        }
        __syncthreads();
        for (int idx = tid; idx < NS_ * CC_; idx += 576) {
            int pt = idx / CC_, c = idx % CC_;
            u.sg.spts[pt][c] = src[(bat * CC_ + c) * NN_ + sidx[pt]];
        }
        __syncthreads();
        for (int idx = tid; idx < NS_ * HH_; idx += 576) {
            int pt = idx >> 6, tt = idx & 63;
            float s = b1[tt];
#pragma unroll
            for (int c = 0; c < CC_; ++c) s += u.sg.spts[pt][c] * W1[c * HH_ + tt];
            u.sg.hs[pt][tt] = fmaxf(s, 0.f);
        }
        __syncthreads();
        for (int idx = tid; idx < NS_ * DD_; idx += 576) {
            int pt = idx >> 5, d = idx & 31;
            float s = b2[d];
#pragma unroll 8
            for (int tt = 0; tt < HH_; ++tt) s += u.sg.hs[pt][tt] * W2[tt * DD_ + d];
            u.sg.sfeat[pt][d] = fmaxf(s, 0.f);
        }
        __syncthreads();
        if (w < 8) {
#pragma unroll
            for (int ss = 0; ss < 4; ++ss) {
                int s = w * 4 + ss;
                float r0 = u.sg.spts[s][0] - c0, r1 = u.sg.spts[s][1] - c1, r2 = u.sg.spts[s][2] - c2;
                float acc = b3[lane] + r0 * W3[0 * HH_ + lane] + r1 * W3[1 * HH_ + lane] + r2 * W3[2 * HH_ + lane];
#pragma unroll 8
                for (int d = 0; d < DD_; ++d) acc += u.sg.sfeat[s][d] * W3[(3 + d) * HH_ + lane];
                u.sg.hs[s][lane] = fmaxf(acc, 0.f);
            }
        }
        __syncthreads();
        for (int idx = tid; idx < NS_ * DD_; idx += 576) {
            int s = idx >> 5, d = idx & 31;
            float o = b4[d];
#pragma unroll 8
            for (int tt = 0; tt < HH_; ++tt) o += u.sg.hs[s][tt] * W4[tt * DD_ + d];
            u.sg.outs[s][d] = fmaxf(o, 0.f);
        }
        __syncthreads();
        if (tid < DD_) {
            float m = -INFINITY;
#pragma unroll 8
            for (int s = 0; s < NS_; ++s) m = fmaxf(m, u.sg.outs[s][tid]);
            (ws + OFF_SDFE)[bk * DD_ + tid] = m;
        }
    }
}

// -------------------- K3: per-candidate MLP + sim + softmax + vcp --------------------
// 128 blocks x 256 threads; thread-per-candidate; ALL array indices compile-time
// (rule #20: runtime-indexed ext arrays go to scratch -> R12's 3.8MB spill traffic).
__global__ __launch_bounds__(256) void simvcp3_kernel(
        const float* __restrict__ tgt,
        const float* __restrict__ W1, const float* __restrict__ b1,
        const float* __restrict__ W2, const float* __restrict__ b2,
        const float* __restrict__ W3, const float* __restrict__ b3,
        const float* __restrict__ W4, const float* __restrict__ b4,
        const float* __restrict__ ws, float* __restrict__ out) {
    __shared__ float sims[NC_];
    __shared__ float sdfe_s[DD_];
    int bk = blockIdx.x;
    int bat = bk / KK_;
    int tid = threadIdx.x;
    const float* xf = ws + OFF_XF + bk * 3;
    float x0 = xf[0], x1 = xf[1], x2 = xf[2];
    if (tid < DD_) sdfe_s[tid] = (ws + OFF_SDFE)[bk * DD_ + tid];
    __syncthreads();
    if (tid < NC_) {
        int c = tid;
        int ix = c / 36, iy = (c / 6) % 6, iz = c % 6;
        float cx = x0 + (ix * 0.4f - 1.0f);
        float cy = x1 + (iy * 0.4f - 1.0f);
        float cz = x2 + (iz * 0.4f - 1.0f);
        int bi = ((const int*)ws)[OFF_NNT + bk * NC_ + c];
        float xc[CC_];
#pragma unroll
        for (int ch = 0; ch < CC_; ++ch) xc[ch] = tgt[(bat * CC_ + ch) * NN_ + bi];
        // tgt fe on demand (identical arithmetic to fe_kernel)
        float h[HH_];
#pragma unroll
        for (int tt = 0; tt < HH_; ++tt) {
            float s = b1[tt];
#pragma unroll
            for (int ch = 0; ch < CC_; ++ch) s += xc[ch] * W1[ch * HH_ + tt];
            h[tt] = fmaxf(s, 0.f);
        }
        float x[3 + DD_];
        x[0] = xc[0] - cx; x[1] = xc[1] - cy; x[2] = xc[2] - cz;
#pragma unroll
        for (int d = 0; d < DD_; ++d) {          // FULL unroll: x[3+d] static index
            float s = b2[d];
#pragma unroll
            for (int tt = 0; tt < HH_; ++tt) s += h[tt] * W2[tt * DD_ + d];
            x[3 + d] = fmaxf(s, 0.f);
        }
        float o[DD_];
#pragma unroll
        for (int d = 0; d < DD_; ++d) o[d] = b4[d];
        for (int tt = 0; tt < HH_; ++tt) {
            float acc = b3[tt];
#pragma unroll
            for (int cc = 0; cc < 3 + DD_; ++cc) acc += x[cc] * W3[cc * HH_ + tt];
            float ht = fmaxf(acc, 0.f);
#pragma unroll
            for (int d = 0; d < DD_; ++d) o[d] += ht * W4[tt * DD_ + d];
        }
        float sim = 0.f;
#pragma unroll
        for (int d = 0; d < DD_; ++d) sim += fmaxf(o[d], 0.f) * sdfe_s[d];
        sims[c] = sim;
    }
    __syncthreads();
    if (tid < 64) {
        int lane = tid;
        float m = -INFINITY;
        for (int c = lane; c < NC_; c += 64) m = fmaxf(m, sims[c]);
#pragma unroll
        for (int sh = 32; sh; sh >>= 1) m = fmaxf(m, __shfl_xor(m, sh));
        float se = 0.f, v0 = 0.f, v1 = 0.f, v2 = 0.f;
        for (int c = lane; c < NC_; c += 64) {
            float e = expf(sims[c] - m);
            int ix = c / 36, iy = (c / 6) % 6, iz = c % 6;
            se += e;
            v0 += e * (x0 + (ix * 0.4f - 1.0f));
            v1 += e * (x1 + (iy * 0.4f - 1.0f));
            v2 += e * (x2 + (iz * 0.4f - 1.0f));
        }
#pragma unroll
        for (int sh = 32; sh; sh >>= 1) {
            se += __shfl_xor(se, sh);
            v0 += __shfl_xor(v0, sh);
            v1 += __shfl_xor(v1, sh);
            v2 += __shfl_xor(v2, sh);
        }
        if (lane == 0) {
            float inv = 1.0f / se;
            float* oo = out + BB_ * KK_ * CC_ + bk * 3;
            oo[0] = v0 * inv;
            oo[1] = v1 * inv;
            oo[2] = v2 * inv;
        }
    }
}

extern "C" void kernel_launch(void* const* d_in, const int* in_sizes, int n_in,
                              void* d_out, int out_size, void* d_ws, size_t ws_size,
                              hipStream_t stream) {
    const float* src = (const float*)d_in[0];
    const float* tgt = (const float*)d_in[1];
    const float* R   = (const float*)d_in[2];
    const float* t   = (const float*)d_in[3];
    const float* W1  = (const float*)d_in[4];
    const float* b1  = (const float*)d_in[5];
    const float* W2  = (const float*)d_in[6];
    const float* b2  = (const float*)d_in[7];
    const float* Wwl = (const float*)d_in[8];
    const float* bwl = (const float*)d_in[9];
    const float* W3  = (const float*)d_in[10];
    const float* b3  = (const float*)d_in[11];
    const float* W4  = (const float*)d_in[12];
    const float* b4  = (const float*)d_in[13];
    float* ws  = (float*)d_ws;
    float* out = (float*)d_out;

    fe_w_kernel<<<16, 256, 0, stream>>>(src, W1, b1, W2, b2, Wwl, bwl, ws);
    mid3_kernel<<<3 * BB_ * KK_, 576, 0, stream>>>(src, tgt, R, t, W1, b1, W2, b2,
                                                   W3, b3, W4, b4, ws, out);
    simvcp3_kernel<<<BB_ * KK_, 256, 0, stream>>>(tgt, W1, b1, W2, b2,
                                                  W3, b3, W4, b4, ws, out);
}

// Round 14
// 87.585 us; speedup vs baseline: 1.8805x; 1.0483x over previous
//
#include <hip/hip_runtime.h>
#include <math.h>

// Problem constants
#define BB_ 2      // batch
#define CC_ 6      // channels
#define NN_ 2048   // points
#define KK_ 64     // keypoints
#define NS_ 32     // neighbors
#define DD_ 32     // feat dim
#define NC_ 216    // candidate grid (6^3)
#define HH_ 64     // hidden dim

// ws layout (element units)
#define OFF_W      0        // 4096 floats
#define OFF_NNT    4096     // 27648 ints (int* view)
#define OFF_XF     31744    // 384 floats (xform per bk)
#define OFF_SDFE   32128    // 4096 floats
#define OFF_TFEAT  36224    // B*N*D = 131072 floats (tgt feats)

// Order-preserving bijection float -> uint32 (ascending)
__device__ __forceinline__ unsigned sortable_f32(float f) {
    unsigned u = __float_as_uint(f);
    return (u & 0x80000000u) ? ~u : (u | 0x80000000u);
}
__device__ __forceinline__ float unsortable_f32(unsigned s) {
    unsigned u = (s & 0x80000000u) ? (s ^ 0x80000000u) : ~s;
    return __uint_as_float(u);
}

__device__ __forceinline__ unsigned long long wave_sort64_asc(unsigned long long key, int lane) {
#pragma unroll
    for (int k = 2; k <= 64; k <<= 1) {
#pragma unroll
        for (int j = k >> 1; j > 0; j >>= 1) {
            unsigned long long other = __shfl_xor(key, j);
            bool lower = (lane & j) == 0;
            bool asc = (lane & k) == 0;
            bool takemin = (lower == asc);
            unsigned long long mn = key < other ? key : other;
            unsigned long long mx = key < other ? other : key;
            key = takemin ? mn : mx;
        }
    }
    return key;
}

__device__ __forceinline__ unsigned long long merge_keep_min64(unsigned long long a, unsigned long long b, int lane) {
    unsigned long long br = __shfl(b, 63 - lane);
    unsigned long long m = a < br ? a : br;
#pragma unroll
    for (int j = 32; j > 0; j >>= 1) {
        unsigned long long other = __shfl_xor(m, j);
        bool lower = (lane & j) == 0;
        unsigned long long mn = m < other ? m : other;
        unsigned long long mx = m < other ? other : m;
        m = lower ? mn : mx;
    }
    return m;
}

// -------------------- K1: src keypoint weights + tgt feats --------------------
__global__ void fe2_kernel(const float* __restrict__ src, const float* __restrict__ tgt,
                           const float* __restrict__ W1, const float* __restrict__ b1,
                           const float* __restrict__ W2, const float* __restrict__ b2,
                           const float* __restrict__ Wwl, const float* __restrict__ bwl,
                           float* __restrict__ ws) {
    int gid = blockIdx.x * blockDim.x + threadIdx.x;   // 0..8191
    int cloud = gid / (BB_ * NN_);
    int r = gid % (BB_ * NN_);
    int b = r / NN_, n = r % NN_;
    const float* pts = cloud ? tgt : src;
    float x[CC_];
#pragma unroll
    for (int c = 0; c < CC_; ++c) x[c] = pts[(b * CC_ + c) * NN_ + n];
    float h[HH_];
#pragma unroll
    for (int t = 0; t < HH_; ++t) {
        float s = b1[t];
#pragma unroll
        for (int c = 0; c < CC_; ++c) s += x[c] * W1[c * HH_ + t];
        h[t] = fmaxf(s, 0.f);
    }
    float* feat = ws + OFF_TFEAT + (size_t)r * DD_;
    float wsum = 0.f;
#pragma unroll 4
    for (int d = 0; d < DD_; ++d) {
        float s = b2[d];
#pragma unroll
        for (int t = 0; t < HH_; ++t) s += h[t] * W2[t * DD_ + d];
        s = fmaxf(s, 0.f);
        if (cloud) feat[d] = s;
        else wsum += s * Wwl[d];
    }
    if (cloud == 0) (ws + OFF_W)[r] = wsum + bwl[0];
}

// -------------------- K2: cand role (256 blocks) + src role (128 blocks) ----
__global__ __launch_bounds__(576) void mid3_kernel(
        const float* __restrict__ src, const float* __restrict__ tgt,
        const float* __restrict__ R, const float* __restrict__ t,
        const float* __restrict__ W1, const float* __restrict__ b1,
        const float* __restrict__ W2, const float* __restrict__ b2,
        const float* __restrict__ W3, const float* __restrict__ b3,
        const float* __restrict__ W4, const float* __restrict__ b4,
        float* __restrict__ ws, float* __restrict__ out) {
    __shared__ union {
        unsigned long long runs[8 * 64];                 // 4 KB (select)
        float4 pk[NN_];                                  // 32 KB (cand)
        struct {
            unsigned long long runs2[8 * 64];
            float spts[NS_][CC_];
            float hs[NS_][HH_];
            float sfeat[NS_][DD_];
            float outs[NS_][DD_];
        } sg;                                            // ~20 KB (src)
    } u;
    __shared__ float bcast[8];
    __shared__ int   sidx[NS_];

    int blk = blockIdx.x;
    int tid = threadIdx.x;
    int w = tid >> 6, lane = tid & 63;
    bool cand_role = (blk < 2 * BB_ * KK_);
    int bk = cand_role ? (blk >> 1) : (blk - 2 * BB_ * KK_);
    int bat = bk / KK_, kth = bk % KK_;
    const float* wbuf = ws + OFF_W;
    int* nntb = (int*)ws + OFF_NNT;

    // ---------- per-block top-K select ----------
    if (w < 8) {
        unsigned long long k4[4];
#pragma unroll
        for (int q = 0; q < 4; ++q) {
            int j = w * 256 + q * 64 + lane;
            k4[q] = ((unsigned long long)(~sortable_f32(wbuf[bat * NN_ + j])) << 32) | (unsigned)j;
        }
        unsigned long long m1 = merge_keep_min64(wave_sort64_asc(k4[0], lane),
                                                 wave_sort64_asc(k4[1], lane), lane);
        unsigned long long m2 = merge_keep_min64(wave_sort64_asc(k4[2], lane),
                                                 wave_sort64_asc(k4[3], lane), lane);
        u.runs[w * 64 + lane] = merge_keep_min64(m1, m2, lane);
    }
    __syncthreads();
#pragma unroll
    for (int lvl = 4; lvl >= 1; lvl >>= 1) {
        unsigned long long r = 0;
        if (w < lvl) r = merge_keep_min64(u.runs[w * 64 + lane], u.runs[(w + lvl) * 64 + lane], lane);
        __syncthreads();
        if (w < lvl) u.runs[w * 64 + lane] = r;
        __syncthreads();
    }
    if (tid == 0) {
        int bi = (int)(u.runs[kth] & 0xFFFFFFFFu);
        float c3[3];
#pragma unroll
        for (int c = 0; c < CC_; ++c) {
            float v = src[(bat * CC_ + c) * NN_ + bi];
            if (!cand_role) out[bk * CC_ + c] = v;       // one writer per bk
            if (c < 3) c3[c] = v;
        }
        bcast[0] = c3[0]; bcast[1] = c3[1]; bcast[2] = c3[2];
#pragma unroll
        for (int i = 0; i < 3; ++i) {
            float xfi;
            {
#pragma clang fp contract(off)
                xfi = ((R[i * 3 + 0] * c3[0] + R[i * 3 + 1] * c3[1]) + R[i * 3 + 2] * c3[2]) + t[i];
            }
            bcast[3 + i] = xfi;
            if (!cand_role) (ws + OFF_XF)[bk * 3 + i] = xfi;
        }
    }
    __syncthreads();

    if (cand_role) {
        // ---------- cand role: NN for 18 xy-groups ----------
        int half = blk & 1;
        for (int j = tid; j < NN_; j += 576) {
            float px = tgt[(bat * CC_ + 0) * NN_ + j];
            float py = tgt[(bat * CC_ + 1) * NN_ + j];
            float pz = tgt[(bat * CC_ + 2) * NN_ + j];
            float pw;
            {
#pragma clang fp contract(off)
                pw = (px * px + py * py) + pz * pz;
            }
            u.pk[j ^ ((j >> 6) & 7)] = make_float4(px, py, pz, pw);
        }
        float x0 = bcast[3], x1 = bcast[4], x2 = bcast[5];
        __syncthreads();

        int lg = tid >> 5;                       // 0..17
        int chunk = tid & 31;
        int grp = half * 18 + lg;                // 0..35 = ix*6+iy
        int ix = grp / 6, iy = grp % 6;
        float cx = x0 + (ix * 0.4f - 1.0f);
        float cy = x1 + (iy * 0.4f - 1.0f);
        float cxy2;
        {
#pragma clang fp contract(off)
            cxy2 = cx * cx + cy * cy;
        }
        float m2x = -2.0f * cx, m2y = -2.0f * cy;
        float aaz[6], m2z[6];
#pragma unroll
        for (int z = 0; z < 6; ++z) {
            float cz = x2 + (z * 0.4f - 1.0f);
            {
#pragma clang fp contract(off)
                aaz[z] = cxy2 + cz * cz;
            }
            m2z[z] = -2.0f * cz;
        }
        float bv[6];
        int bi6[6];
#pragma unroll
        for (int z = 0; z < 6; ++z) { bv[z] = INFINITY; bi6[z] = 0; }
        int base = chunk * 64;
        int sw = chunk & 7;
        for (int i = 0; i < 64; ++i) {
            int j = base + i;                    // ascending j -> first-index ties
            float4 p = u.pk[base + (i ^ sw)];    // slot(j) for j=base+i
            float txy;
            {
#pragma clang fp contract(off)
                txy = m2x * p.x + m2y * p.y;
            }
#pragma unroll
            for (int z = 0; z < 6; ++z) {
                float d2;
                {
#pragma clang fp contract(off)
                    d2 = (aaz[z] + p.w) + (txy + m2z[z] * p.z);
                }
                if (d2 < bv[z]) { bv[z] = d2; bi6[z] = j; }
            }
        }
#pragma unroll
        for (int z = 0; z < 6; ++z) {
            unsigned long long key = ((unsigned long long)sortable_f32(bv[z]) << 32) | (unsigned)bi6[z];
#pragma unroll
            for (int m = 1; m <= 16; m <<= 1) {
                unsigned long long other = __shfl_xor(key, m);
                key = other < key ? other : key;
            }
            if (chunk == 0) nntb[bk * NC_ + grp * 6 + z] = (int)(key & 0xFFFFFFFFu);
        }
    } else {
        // ---------- src role: grouping + on-demand feats + dfe + max ----------
        float c0 = bcast[0], c1 = bcast[1], c2 = bcast[2];
        float aa;
        {
#pragma clang fp contract(off)
            aa = (c0 * c0 + c1 * c1) + c2 * c2;
        }
        float m2x = -2.0f * c0, m2y = -2.0f * c1, m2z = -2.0f * c2;
        if (w < 8) {
            unsigned long long k4[4];
#pragma unroll
            for (int q = 0; q < 4; ++q) {
                int j = w * 256 + q * 64 + lane;
                float px = src[(bat * CC_ + 0) * NN_ + j];
                float py = src[(bat * CC_ + 1) * NN_ + j];
                float pz = src[(bat * CC_ + 2) * NN_ + j];
                float d2;
                {
#pragma clang fp contract(off)
                    float pw = (px * px + py * py) + pz * pz;
                    d2 = (aa + pw) + ((m2x * px + m2y * py) + m2z * pz);
                }
                k4[q] = ((unsigned long long)sortable_f32(d2) << 32) | (unsigned)j;
            }
            unsigned long long m1 = merge_keep_min64(wave_sort64_asc(k4[0], lane),
                                                     wave_sort64_asc(k4[1], lane), lane);
            unsigned long long m2 = merge_keep_min64(wave_sort64_asc(k4[2], lane),
                                                     wave_sort64_asc(k4[3], lane), lane);
            u.sg.runs2[w * 64 + lane] = merge_keep_min64(m1, m2, lane);
        }
        __syncthreads();
#pragma unroll
        for (int lvl = 4; lvl >= 1; lvl >>= 1) {
            unsigned long long r = 0;
            if (w < lvl) r = merge_keep_min64(u.sg.runs2[w * 64 + lane], u.sg.runs2[(w + lvl) * 64 + lane], lane);
            __syncthreads();
            if (w < lvl) u.sg.runs2[w * 64 + lane] = r;
            __syncthreads();
        }
        if (tid < NS_) {
            unsigned long long key = u.sg.runs2[tid];
            unsigned long long key0 = u.sg.runs2[0];
            float dd = unsortable_f32((unsigned)(key >> 32));
            sidx[tid] = (dd <= 1.0f) ? (int)(key & 0xFFFFFFFFu) : (int)(key0 & 0xFFFFFFFFu);  // R^2=1
        }
        __syncthreads();
        for (int idx = tid; idx < NS_ * CC_; idx += 576) {
            int pt = idx / CC_, c = idx % CC_;
            u.sg.spts[pt][c] = src[(bat * CC_ + c) * NN_ + sidx[pt]];
        }
        __syncthreads();
        for (int idx = tid; idx < NS_ * HH_; idx += 576) {
            int pt = idx >> 6, tt = idx & 63;
            float s = b1[tt];
#pragma unroll
            for (int c = 0; c < CC_; ++c) s += u.sg.spts[pt][c] * W1[c * HH_ + tt];
            u.sg.hs[pt][tt] = fmaxf(s, 0.f);
        }
        __syncthreads();
        for (int idx = tid; idx < NS_ * DD_; idx += 576) {
            int pt = idx >> 5, d = idx & 31;
            float s = b2[d];
#pragma unroll 8
            for (int tt = 0; tt < HH_; ++tt) s += u.sg.hs[pt][tt] * W2[tt * DD_ + d];
            u.sg.sfeat[pt][d] = fmaxf(s, 0.f);
        }
        __syncthreads();
        if (w < 8) {
#pragma unroll
            for (int ss = 0; ss < 4; ++ss) {
                int s = w * 4 + ss;
                float r0 = u.sg.spts[s][0] - c0, r1 = u.sg.spts[s][1] - c1, r2 = u.sg.spts[s][2] - c2;
                float acc = b3[lane] + r0 * W3[0 * HH_ + lane] + r1 * W3[1 * HH_ + lane] + r2 * W3[2 * HH_ + lane];
#pragma unroll 8
                for (int d = 0; d < DD_; ++d) acc += u.sg.sfeat[s][d] * W3[(3 + d) * HH_ + lane];
                u.sg.hs[s][lane] = fmaxf(acc, 0.f);
            }
        }
        __syncthreads();
        for (int idx = tid; idx < NS_ * DD_; idx += 576) {
            int s = idx >> 5, d = idx & 31;
            float o = b4[d];
#pragma unroll 8
            for (int tt = 0; tt < HH_; ++tt) o += u.sg.hs[s][tt] * W4[tt * DD_ + d];
            u.sg.outs[s][d] = fmaxf(o, 0.f);
        }
        __syncthreads();
        if (tid < DD_) {
            float m = -INFINITY;
#pragma unroll 8
            for (int s = 0; s < NS_; ++s) m = fmaxf(m, u.sg.outs[s][tid]);
            (ws + OFF_SDFE)[bk * DD_ + tid] = m;
        }
    }
}

// -------------------- K3: per-candidate MLP + sim + softmax + vcp --------------------
// 128 blocks x 256 threads; thread-per-candidate; tgt feat PRELOADED from ws
// (no h[64] recompute -> short chain, registers only; rule #20 respected).
__global__ __launch_bounds__(256) void simvcp4_kernel(
        const float* __restrict__ tgt,
        const float* __restrict__ W3, const float* __restrict__ b3,
        const float* __restrict__ W4, const float* __restrict__ b4,
        const float* __restrict__ ws, float* __restrict__ out) {
    __shared__ float sims[NC_];
    __shared__ float sdfe_s[DD_];
    int bk = blockIdx.x;
    int bat = bk / KK_;
    int tid = threadIdx.x;
    const float* xf = ws + OFF_XF + bk * 3;
    float x0 = xf[0], x1 = xf[1], x2 = xf[2];
    if (tid < DD_) sdfe_s[tid] = (ws + OFF_SDFE)[bk * DD_ + tid];
    __syncthreads();
    if (tid < NC_) {
        int c = tid;
        int ix = c / 36, iy = (c / 6) % 6, iz = c % 6;
        float cx = x0 + (ix * 0.4f - 1.0f);
        float cy = x1 + (iy * 0.4f - 1.0f);
        float cz = x2 + (iz * 0.4f - 1.0f);
        int bi = ((const int*)ws)[OFF_NNT + bk * NC_ + c];
        float x[3 + DD_];
        x[0] = tgt[(bat * CC_ + 0) * NN_ + bi] - cx;
        x[1] = tgt[(bat * CC_ + 1) * NN_ + bi] - cy;
        x[2] = tgt[(bat * CC_ + 2) * NN_ + bi] - cz;
        const float* f = ws + OFF_TFEAT + ((size_t)(bat * NN_ + bi)) * DD_;
#pragma unroll
        for (int d = 0; d < DD_; ++d) x[3 + d] = f[d];
        float o[DD_];
#pragma unroll
        for (int d = 0; d < DD_; ++d) o[d] = b4[d];
        for (int tt = 0; tt < HH_; ++tt) {
            float acc = b3[tt];
#pragma unroll
            for (int cc = 0; cc < 3 + DD_; ++cc) acc += x[cc] * W3[cc * HH_ + tt];
            float ht = fmaxf(acc, 0.f);
#pragma unroll
            for (int d = 0; d < DD_; ++d) o[d] += ht * W4[tt * DD_ + d];
        }
        float sim = 0.f;
#pragma unroll
        for (int d = 0; d < DD_; ++d) sim += fmaxf(o[d], 0.f) * sdfe_s[d];
        sims[c] = sim;
    }
    __syncthreads();
    if (tid < 64) {
        int lane = tid;
        float m = -INFINITY;
        for (int c = lane; c < NC_; c += 64) m = fmaxf(m, sims[c]);
#pragma unroll
        for (int sh = 32; sh; sh >>= 1) m = fmaxf(m, __shfl_xor(m, sh));
        float se = 0.f, v0 = 0.f, v1 = 0.f, v2 = 0.f;
        for (int c = lane; c < NC_; c += 64) {
            float e = expf(sims[c] - m);
            int ix = c / 36, iy = (c / 6) % 6, iz = c % 6;
            se += e;
            v0 += e * (x0 + (ix * 0.4f - 1.0f));
            v1 += e * (x1 + (iy * 0.4f - 1.0f));
            v2 += e * (x2 + (iz * 0.4f - 1.0f));
        }
#pragma unroll
        for (int sh = 32; sh; sh >>= 1) {
            se += __shfl_xor(se, sh);
            v0 += __shfl_xor(v0, sh);
            v1 += __shfl_xor(v1, sh);
            v2 += __shfl_xor(v2, sh);
        }
        if (lane == 0) {
            float inv = 1.0f / se;
            float* oo = out + BB_ * KK_ * CC_ + bk * 3;
            oo[0] = v0 * inv;
            oo[1] = v1 * inv;
            oo[2] = v2 * inv;
        }
    }
}

extern "C" void kernel_launch(void* const* d_in, const int* in_sizes, int n_in,
                              void* d_out, int out_size, void* d_ws, size_t ws_size,
                              hipStream_t stream) {
    const float* src = (const float*)d_in[0];
    const float* tgt = (const float*)d_in[1];
    const float* R   = (const float*)d_in[2];
    const float* t   = (const float*)d_in[3];
    const float* W1  = (const float*)d_in[4];
    const float* b1  = (const float*)d_in[5];
    const float* W2  = (const float*)d_in[6];
    const float* b2  = (const float*)d_in[7];
    const float* Wwl = (const float*)d_in[8];
    const float* bwl = (const float*)d_in[9];
    const float* W3  = (const float*)d_in[10];
    const float* b3  = (const float*)d_in[11];
    const float* W4  = (const float*)d_in[12];
    const float* b4  = (const float*)d_in[13];
    float* ws  = (float*)d_ws;
    float* out = (float*)d_out;

    fe2_kernel<<<32, 256, 0, stream>>>(src, tgt, W1, b1, W2, b2, Wwl, bwl, ws);
    mid3_kernel<<<3 * BB_ * KK_, 576, 0, stream>>>(src, tgt, R, t, W1, b1, W2, b2,
                                                   W3, b3, W4, b4, ws, out);
    simvcp4_kernel<<<BB_ * KK_, 256, 0, stream>>>(tgt, W3, b3, W4, b4, ws, out);
}